// Round 5
// baseline (15157.904 us; speedup 1.0000x reference)
//
#include <hip/hip_runtime.h>
#include <stdint.h>

#define Bq 64
#define Tq 512
#define Hq 512
#define G3 1536

typedef unsigned short u16;
typedef uint32_t u32;
typedef unsigned long long u64;
typedef __attribute__((ext_vector_type(8))) short bf16x8;
typedef __attribute__((ext_vector_type(4))) float f32x4;

__device__ __forceinline__ float bf2f(u16 v){ unsigned u = ((unsigned)v)<<16; float f; __builtin_memcpy(&f,&u,4); return f; }
__device__ __forceinline__ u16 f2bf(float f){ unsigned u; __builtin_memcpy(&u,&f,4); u += 0x7fffu + ((u>>16)&1u); return (u16)(u>>16); }

// dtype detector: flag=1 if inputs are bf16, 0 if fp32.
__global__ void detect_k(const u16* __restrict__ xs, int* __restrict__ flag){
  __shared__ int cnt;
  if (threadIdx.x==0) cnt = 0;
  __syncthreads();
  int good = 0;
  for (int i = threadIdx.x; i < 4096; i += 256) {
    u16 v = xs[2*i];
    int e = (v>>7)&0xFF;
    if (e==0 || (e>=100 && e<=140)) good++;
  }
  atomicAdd(&cnt, good);
  __syncthreads();
  if (threadIdx.x==0) flag[0] = (cnt > 3600) ? 1 : 0;
}

// ---------------------------------------------------------------------------
// gx GEMM: gx[dir][t][b][n] = A[b*T+t][:] . W[dir][n][:] + bias[dir][n]
// AMODE 0: A dtype per flag (fp32 -> split hi/lo bf16). AMODE 1: A bf16 (hs0).
// OUTF32: gx stored fp32 (1) or bf16 (0).
// ---------------------------------------------------------------------------
template<int K, int AMODE, int OUTF32>
__global__ __launch_bounds__(256,1) void gemm_gx(const void* __restrict__ Araw,
        const void* __restrict__ Wraw, const void* __restrict__ braw,
        void* __restrict__ outraw, const int* __restrict__ dflag)
{
  __shared__ __align__(16) u16 Ah[64*72];
  __shared__ __align__(16) u16 Al[64*72];
  __shared__ __align__(16) u16 Wh[64*72];
  __shared__ __align__(16) u16 Wl[64*72];
  const int bf16in = dflag[0];
  const bool useAlo = (AMODE==0) && !bf16in;
  const bool useWlo = !bf16in;
  const int dir = blockIdx.z;
  const int tid = threadIdx.x;
  const int m0 = blockIdx.x*64, n0 = blockIdx.y*64;
  const int wave = tid>>6, lane = tid&63;
  const int wm = (wave>>1)*32, wn = (wave&1)*32;
  f32x4 acc[2][2] = {};

  for (int kb=0; kb<K/64; kb++) {
    if (AMODE==0 && !bf16in) {
      const float* Af = (const float*)Araw;
      #pragma unroll
      for (int it=0; it<4; it++) {
        int c = it*256 + tid;
        int r = c>>4, cc = (c&15)*4;
        float4 v = *(const float4*)&Af[(size_t)(m0+r)*K + kb*64 + cc];
        u16 h0=f2bf(v.x), h1=f2bf(v.y), h2=f2bf(v.z), h3=f2bf(v.w);
        *(ushort4*)&Ah[r*72+cc] = make_ushort4(h0,h1,h2,h3);
        *(ushort4*)&Al[r*72+cc] = make_ushort4(
            f2bf(v.x-bf2f(h0)), f2bf(v.y-bf2f(h1)),
            f2bf(v.z-bf2f(h2)), f2bf(v.w-bf2f(h3)));
      }
    } else {
      const u16* Ab = (const u16*)Araw;
      #pragma unroll
      for (int it=0; it<2; it++) {
        int c = it*256 + tid;
        int r = c>>3, cc = (c&7)*8;
        *(bf16x8*)&Ah[r*72+cc] = *(const bf16x8*)&Ab[(size_t)(m0+r)*K + kb*64 + cc];
      }
    }
    if (!bf16in) {
      const float* Wf = (const float*)Wraw + (size_t)dir*G3*K;
      #pragma unroll
      for (int it=0; it<4; it++) {
        int c = it*256 + tid;
        int r = c>>4, cc = (c&15)*4;
        float4 v = *(const float4*)&Wf[(size_t)(n0+r)*K + kb*64 + cc];
        u16 h0=f2bf(v.x), h1=f2bf(v.y), h2=f2bf(v.z), h3=f2bf(v.w);
        *(ushort4*)&Wh[r*72+cc] = make_ushort4(h0,h1,h2,h3);
        *(ushort4*)&Wl[r*72+cc] = make_ushort4(
            f2bf(v.x-bf2f(h0)), f2bf(v.y-bf2f(h1)),
            f2bf(v.z-bf2f(h2)), f2bf(v.w-bf2f(h3)));
      }
    } else {
      const u16* Wb = (const u16*)Wraw + (size_t)dir*G3*K;
      #pragma unroll
      for (int it=0; it<2; it++) {
        int c = it*256 + tid;
        int r = c>>3, cc = (c&7)*8;
        *(bf16x8*)&Wh[r*72+cc] = *(const bf16x8*)&Wb[(size_t)(n0+r)*K + kb*64 + cc];
      }
    }
    __syncthreads();
    #pragma unroll
    for (int ks=0; ks<2; ks++) {
      int ko = ks*32 + (lane>>4)*8;
      bf16x8 a0 = *(const bf16x8*)&Ah[(wm    + (lane&15))*72 + ko];
      bf16x8 a1 = *(const bf16x8*)&Ah[(wm+16 + (lane&15))*72 + ko];
      bf16x8 b0 = *(const bf16x8*)&Wh[(wn    + (lane&15))*72 + ko];
      bf16x8 b1 = *(const bf16x8*)&Wh[(wn+16 + (lane&15))*72 + ko];
      acc[0][0] = __builtin_amdgcn_mfma_f32_16x16x32_bf16(a0,b0,acc[0][0],0,0,0);
      acc[0][1] = __builtin_amdgcn_mfma_f32_16x16x32_bf16(a0,b1,acc[0][1],0,0,0);
      acc[1][0] = __builtin_amdgcn_mfma_f32_16x16x32_bf16(a1,b0,acc[1][0],0,0,0);
      acc[1][1] = __builtin_amdgcn_mfma_f32_16x16x32_bf16(a1,b1,acc[1][1],0,0,0);
      if (useAlo) {
        bf16x8 c0 = *(const bf16x8*)&Al[(wm    + (lane&15))*72 + ko];
        bf16x8 c1 = *(const bf16x8*)&Al[(wm+16 + (lane&15))*72 + ko];
        acc[0][0] = __builtin_amdgcn_mfma_f32_16x16x32_bf16(c0,b0,acc[0][0],0,0,0);
        acc[0][1] = __builtin_amdgcn_mfma_f32_16x16x32_bf16(c0,b1,acc[0][1],0,0,0);
        acc[1][0] = __builtin_amdgcn_mfma_f32_16x16x32_bf16(c1,b0,acc[1][0],0,0,0);
        acc[1][1] = __builtin_amdgcn_mfma_f32_16x16x32_bf16(c1,b1,acc[1][1],0,0,0);
      }
      if (useWlo) {
        bf16x8 d0 = *(const bf16x8*)&Wl[(wn    + (lane&15))*72 + ko];
        bf16x8 d1 = *(const bf16x8*)&Wl[(wn+16 + (lane&15))*72 + ko];
        acc[0][0] = __builtin_amdgcn_mfma_f32_16x16x32_bf16(a0,d0,acc[0][0],0,0,0);
        acc[0][1] = __builtin_amdgcn_mfma_f32_16x16x32_bf16(a0,d1,acc[0][1],0,0,0);
        acc[1][0] = __builtin_amdgcn_mfma_f32_16x16x32_bf16(a1,d0,acc[1][0],0,0,0);
        acc[1][1] = __builtin_amdgcn_mfma_f32_16x16x32_bf16(a1,d1,acc[1][1],0,0,0);
      }
    }
    __syncthreads();
  }
  #pragma unroll
  for (int i=0;i<2;i++) {
    #pragma unroll
    for (int j=0;j<2;j++) {
      int nn = n0 + wn + j*16 + (lane&15);
      float bv = bf16in ? bf2f(((const u16*)braw)[dir*G3 + nn])
                        : ((const float*)braw)[dir*G3 + nn];
      #pragma unroll
      for (int r=0;r<4;r++) {
        int mm = m0 + wm + i*16 + (lane>>4)*4 + r;
        int b = mm >> 9, t = mm & 511;
        size_t oi = ((size_t)(dir*Tq + t)*Bq + b)*G3 + nn;
        float v = acc[i][j][r] + bv;
        if (OUTF32) ((float*)outraw)[oi] = v;
        else        ((u16*)outraw)[oi]   = f2bf(v);
      }
    }
  }
}

// ---------------------------------------------------------------------------
// Persistent GRU scan. 256 wgs: dir(2) x batch-group(8, 8 batches each) x
// slice(16). Same coherence-point protocol as the round-4 PASS (unchanged):
//   producer: atomic-EXCHANGE publishes (execute+ack at MALL), per-wave
//             s_waitcnt vmcnt(0), then lane0 of each PUBLISHING wave (4)
//             fetch_add on the slice counter.
//   consumer: RMW poll (fetch_add 0 -> always fresh), ONE acquire fence
//             (buffer_inv) per step, barrier, relaxed-atomic u64 gathers.
// Flags: 256 logical counters packed 2-per-u32 (groups g,g+1 share a word;
// odd group adds 1<<16; max count 4*512=2048 << 65536, no carry).
// MFMA uses M=16 with batch rows 8..15 zeroed once -> rows 0..7 results are
// bit-identical to the 16-batch version (rows independent in 16x16x32 MFMA).
// ---------------------------------------------------------------------------
template<int LAYER, int GXF32>
__global__ __launch_bounds__(384,1) void gru_scan(const void* __restrict__ whh,
        const void* __restrict__ bhh, const void* __restrict__ gx,
        u16* __restrict__ hs0, void* __restrict__ dout,
        u32* __restrict__ hexw, u32* __restrict__ flags,
        const int* __restrict__ dflag)
{
  extern __shared__ char smem[];
  u16*   wlds = (u16*)smem;                 // 96 x 520 bf16 = 99840 B
  u16*   ht   = (u16*)(smem + 99840);       // 16 x 520 bf16 = 16640 B
  float* ghl  = (float*)(smem + 116480);    // 16 x 100 f32  =  6400 B
  float* bhl  = (float*)(smem + 122880);    // 96 f32        =   384 B (total 123264)
  u32*   htw  = (u32*)ht;

  const int bf16in = dflag[0];
  const int tid = threadIdx.x;
  const int bx  = blockIdx.x;
  const int dir = bx>>7, group=(bx>>4)&7, slice=bx&15;
  const int jbase = slice*32, bg0 = group*8;
  const int dpair = (dir*8 + group) >> 1;      // paired flag word group
  const u32 shift = (u32)(group & 1) * 16u;    // which half of the word
  u32* fl = flags + dpair*16;

  if (!bf16in) {
    const float* wf = (const float*)whh + (size_t)dir*G3*Hq;
    for (int c = tid; c < 96*128; c += 384) {
      int r = c>>7, q = (c&127)*4;
      int gate = r>>5, jj = r&31;
      float4 v = *(const float4*)&wf[(size_t)(gate*512 + jbase + jj)*Hq + q];
      *(ushort4*)&wlds[r*520 + q] = make_ushort4(f2bf(v.x),f2bf(v.y),f2bf(v.z),f2bf(v.w));
    }
  } else {
    const u16* wb = (const u16*)whh + (size_t)dir*G3*Hq;
    for (int c = tid; c < 96*64; c += 384) {
      int r = c>>6, cc = (c&63)*8;
      int gate = r>>5, jj = r&31;
      *(bf16x8*)&wlds[r*520 + cc] = *(const bf16x8*)&wb[(size_t)(gate*512 + jbase + jj)*Hq + cc];
    }
  }
  if (tid < 96) {
    int gate = tid>>5, jj = tid&31;
    int off = dir*G3 + gate*512 + jbase + jj;
    bhl[tid] = bf16in ? bf2f(((const u16*)bhh)[off]) : ((const float*)bhh)[off];
  }
  // zero ht batch rows 8..15 once (never written by the 8-row gather);
  // MFMA reads them but zero A-rows cannot affect rows 0..7 results.
  for (int i = tid; i < 8*260; i += 384) htw[2080 + i] = 0;
  __syncthreads();

  const int lane = tid&63;
  const int n0w = (tid>>6)*16;   // 6 waves cover 96 gate columns

  // per-thread element ownership (static across all steps -> h lives in regs)
  const int b0 = tid>>5, j0 = tid&31;      // valid if tid<256 (8 batches x 32 j)
  const bool act = (tid < 256);
  float h0 = 0.f;
  float gr0,gz0,gn0;
  gr0=gz0=gn0=0.f;

  auto ldgx = [&](int t_in_, float& gr, float& gz, float& gn){
    size_t gbase = ((size_t)(dir*Tq + t_in_)*Bq + (bg0 + b0))*G3 + jbase + j0;
    if (GXF32) { const float* gp=(const float*)gx + gbase; gr=gp[0]; gz=gp[512]; gn=gp[1024]; }
    else       { const u16* gp=(const u16*)gx + gbase; gr=bf2f(gp[0]); gz=bf2f(gp[512]); gn=bf2f(gp[1024]); }
  };
  if (act) {
    int t0 = dir ? (Tq-1) : 0;
    ldgx(t0, gr0, gz0, gn0);
  }

  for (int s=0; s<Tq; s++) {
    const int t_in = dir ? (Tq-1-s) : s;
    // RMW poll: executes at the coherence point -> fresh every round trip.
    if (tid < 16) {
      while (((__hip_atomic_fetch_add(&fl[tid], 0u, __ATOMIC_RELAXED, __HIP_MEMORY_SCOPE_AGENT) >> shift) & 0xffffu) < (u32)(4*s)) {}
    }
    // one acquire fence per step: invalidates stale L2 lines before gather
    __builtin_amdgcn_fence(__ATOMIC_ACQUIRE, "agent");
    __syncthreads();                                   // (A) flags -> gather
    {
      const u32 rb = (u32)(((s&1)*2 + dir)*Bq + bg0)*256u;
      for (int c = tid; c < 8*128; c += 384) {
        int r = c>>7, w2 = c&127;
        u64 v = __hip_atomic_load((const u64*)&hexw[rb + (u32)r*256u + (u32)(2*w2)],
                                  __ATOMIC_RELAXED, __HIP_MEMORY_SCOPE_AGENT);
        *(u64*)&htw[r*260 + 2*w2] = v;
      }
    }
    __syncthreads();                                   // (B) gather -> MFMA
    f32x4 acc = {0.f,0.f,0.f,0.f};
    #pragma unroll
    for (int kk=0; kk<16; kk++) {
      int ko = kk*32 + (lane>>4)*8;
      bf16x8 a = *(const bf16x8*)&ht  [ (lane&15)       *520 + ko];
      bf16x8 b = *(const bf16x8*)&wlds[(n0w + (lane&15))*520 + ko];
      acc = __builtin_amdgcn_mfma_f32_16x16x32_bf16(a,b,acc,0,0,0);
    }
    #pragma unroll
    for (int r=0;r<4;r++) ghl[((lane>>4)*4 + r)*100 + n0w + (lane&15)] = acc[r];
    __syncthreads();                                   // (C) ghl -> elementwise

    // ---- elementwise (gx already in registers), h carried in registers ----
    const u32 rb2 = (u32)((((s+1)&1)*2 + dir)*Bq + bg0)*256u;
    float hn0 = 0.f;
    u16 hb0 = 0;
    if (act) {
      float rr = gr0 + ghl[b0*100 + j0]      + bhl[j0];
      float zz = gz0 + ghl[b0*100 + 32 + j0] + bhl[32 + j0];
      float gh =       ghl[b0*100 + 64 + j0] + bhl[64 + j0];
      float r = 1.f/(1.f + __expf(-rr));
      float z = 1.f/(1.f + __expf(-zz));
      float x = gn0 + r*gh;
      x = fminf(fmaxf(x, -15.f), 15.f);
      float e2 = __expf(2.f*x);
      float n = (e2 - 1.f)/(e2 + 1.f);
      hn0 = (1.f - z)*n + z*h0;
      h0 = hn0; hb0 = f2bf(hn0);
    }
    // ---- publish 4 h values per u64 atomic EXCHANGE (acks at MALL) ----
    if (act) {
      u32 p0 = hb0;
      u32 p1 = (u32)__shfl_down((int)hb0, 1);
      u32 p2 = (u32)__shfl_down((int)hb0, 2);
      u32 p3 = (u32)__shfl_down((int)hb0, 3);
      if ((tid & 3) == 0) {
        u64 pk = (u64)(p0 & 0xffffu) | ((u64)(p1 & 0xffffu) << 16)
               | ((u64)(p2 & 0xffffu) << 32) | ((u64)(p3 & 0xffffu) << 48);
        u64* dst = (u64*)&hexw[rb2 + (u32)b0*256u + (u32)(slice*16 + (j0>>1))];
        (void)__hip_atomic_exchange(dst, pk, __ATOMIC_RELAXED, __HIP_MEMORY_SCOPE_AGENT);
      }
    }
    // per-wave: drain this wave's exchanges (acked at MALL), then signal.
    asm volatile("s_waitcnt vmcnt(0)" ::: "memory");
    if ((tid & 63) == 0 && tid < 256) {
      (void)__hip_atomic_fetch_add(&fl[slice], (1u << shift), __ATOMIC_RELAXED, __HIP_MEMORY_SCOPE_AGENT);
    }

    // ---- prefetch next step's gx (hides under next poll/exchange) ----
    if (act && s+1 < Tq) {
      int tn = dir ? (Tq-2-s) : (s+1);
      ldgx(tn, gr0, gz0, gn0);
    }

    // ---- off-critical-path output stores (nontemporal: keep L2 clean) ----
    if (act) {
      int bg = bg0 + b0;
      size_t oi = ((size_t)bg*Tq + t_in)*1024 + dir*512 + jbase + j0;
      if (LAYER==0) {
        __builtin_nontemporal_store(hb0, &hs0[oi]);
      } else {
        if (bf16in) __builtin_nontemporal_store(hb0, &((u16*)dout)[oi]);
        else        __builtin_nontemporal_store(hn0, &((float*)dout)[oi]);
      }
      if (s == Tq-1) {
        size_t hyi = (size_t)Bq*Tq*1024 + ((size_t)(LAYER*2 + dir)*Bq + bg)*512 + jbase + j0;
        if (bf16in) ((u16*)dout)[hyi] = hb0;
        else        ((float*)dout)[hyi] = hn0;
      }
    }
  }
}

__global__ void init_k(u32* hexw, u32* flags){
  int i = blockIdx.x*256 + threadIdx.x;
  if (i < 2*2*Bq*256) hexw[i] = 0;
  if (i < 128) flags[i] = 0;
}

extern "C" void kernel_launch(void* const* d_in, const int* in_sizes, int n_in,
                              void* d_out, int out_size, void* d_ws, size_t ws_size,
                              hipStream_t stream)
{
  const void* xs    = d_in[0];
  const void* w_ih0 = d_in[1];
  const void* w_hh0 = d_in[2];
  const void* b_ih0 = d_in[3];
  const void* b_hh0 = d_in[4];
  const void* w_ih1 = d_in[5];
  const void* w_hh1 = d_in[6];
  const void* b_ih1 = d_in[7];
  const void* b_hh1 = d_in[8];
  (void)in_sizes; (void)n_in; (void)out_size;

  // ws layout, smalls first: dflag @0, flags @256 (128 u32, packed dual
  // counters), hexw @1024 (262144 B), gx @263168: fp32 (402653184 B) if it
  // fits, else bf16 (201326592 B).
  char* ws   = (char*)d_ws;
  int* dflag = (int*)ws;
  u32* flags = (u32*)(ws + 256);
  u32* hexw  = (u32*)(ws + 1024);
  void* gx   = (void*)(ws + 263168ULL);
  const bool gxf32 = ws_size >= 263168ULL + 402653184ULL;
  // hs0: bf16 scratch in d_out bytes [0, 67 MB); gemm1 consumes it before
  // scan1 overwrites d_out with h1_out (stream-ordered).
  u16* hs0   = (u16*)d_out;

  hipFuncSetAttribute((const void*)gru_scan<0,0>, hipFuncAttributeMaxDynamicSharedMemorySize, 123264);
  hipFuncSetAttribute((const void*)gru_scan<1,0>, hipFuncAttributeMaxDynamicSharedMemorySize, 123264);
  hipFuncSetAttribute((const void*)gru_scan<0,1>, hipFuncAttributeMaxDynamicSharedMemorySize, 123264);
  hipFuncSetAttribute((const void*)gru_scan<1,1>, hipFuncAttributeMaxDynamicSharedMemorySize, 123264);

  dim3 gg(Tq*Bq/64, G3/64, 2);   // (512, 24, 2)

  detect_k<<<1, 256, 0, stream>>>((const u16*)xs, dflag);
  init_k<<<512, 256, 0, stream>>>(hexw, flags);
  if (gxf32) {
    gemm_gx<512,0,1><<<gg, 256, 0, stream>>>(xs, w_ih0, b_ih0, gx, dflag);
    gru_scan<0,1><<<256, 384, 123264, stream>>>(w_hh0, b_hh0, gx, hs0, d_out, hexw, flags, dflag);
    gemm_gx<1024,1,1><<<gg, 256, 0, stream>>>(hs0, w_ih1, b_ih1, gx, dflag);
    init_k<<<512, 256, 0, stream>>>(hexw, flags);
    gru_scan<1,1><<<256, 384, 123264, stream>>>(w_hh1, b_hh1, gx, hs0, d_out, hexw, flags, dflag);
  } else {
    gemm_gx<512,0,0><<<gg, 256, 0, stream>>>(xs, w_ih0, b_ih0, gx, dflag);
    gru_scan<0,0><<<256, 384, 123264, stream>>>(w_hh0, b_hh0, gx, hs0, d_out, hexw, flags, dflag);
    gemm_gx<1024,1,0><<<gg, 256, 0, stream>>>(hs0, w_ih1, b_ih1, gx, dflag);
    init_k<<<512, 256, 0, stream>>>(hexw, flags);
    gru_scan<1,0><<<256, 384, 123264, stream>>>(w_hh1, b_hh1, gx, hs0, d_out, hexw, flags, dflag);
  }
}

// Round 6
// 6972.675 us; speedup vs baseline: 2.1739x; 2.1739x over previous
//
#include <hip/hip_runtime.h>
#include <stdint.h>

#define Bq 64
#define Tq 512
#define Hq 512
#define G3 1536

typedef unsigned short u16;
typedef uint32_t u32;
typedef unsigned long long u64;
typedef __attribute__((ext_vector_type(8))) short bf16x8;
typedef __attribute__((ext_vector_type(4))) float f32x4;

__device__ __forceinline__ float bf2f(u16 v){ unsigned u = ((unsigned)v)<<16; float f; __builtin_memcpy(&f,&u,4); return f; }
__device__ __forceinline__ u16 f2bf(float f){ unsigned u; __builtin_memcpy(&u,&f,4); u += 0x7fffu + ((u>>16)&1u); return (u16)(u>>16); }

// dtype detector: flag=1 if inputs are bf16, 0 if fp32.
__global__ void detect_k(const u16* __restrict__ xs, int* __restrict__ flag){
  __shared__ int cnt;
  if (threadIdx.x==0) cnt = 0;
  __syncthreads();
  int good = 0;
  for (int i = threadIdx.x; i < 4096; i += 256) {
    u16 v = xs[2*i];
    int e = (v>>7)&0xFF;
    if (e==0 || (e>=100 && e<=140)) good++;
  }
  atomicAdd(&cnt, good);
  __syncthreads();
  if (threadIdx.x==0) flag[0] = (cnt > 3600) ? 1 : 0;
}

// ---------------------------------------------------------------------------
// gx GEMM: gx[dir][t][b][n] = A[b*T+t][:] . W[dir][n][:] + bias[dir][n]
// AMODE 0: A dtype per flag (fp32 -> split hi/lo bf16). AMODE 1: A bf16 (hs0).
// OUTF32: gx stored fp32 (1) or bf16 (0).
// ---------------------------------------------------------------------------
template<int K, int AMODE, int OUTF32>
__global__ __launch_bounds__(256,1) void gemm_gx(const void* __restrict__ Araw,
        const void* __restrict__ Wraw, const void* __restrict__ braw,
        void* __restrict__ outraw, const int* __restrict__ dflag)
{
  __shared__ __align__(16) u16 Ah[64*72];
  __shared__ __align__(16) u16 Al[64*72];
  __shared__ __align__(16) u16 Wh[64*72];
  __shared__ __align__(16) u16 Wl[64*72];
  const int bf16in = dflag[0];
  const bool useAlo = (AMODE==0) && !bf16in;
  const bool useWlo = !bf16in;
  const int dir = blockIdx.z;
  const int tid = threadIdx.x;
  const int m0 = blockIdx.x*64, n0 = blockIdx.y*64;
  const int wave = tid>>6, lane = tid&63;
  const int wm = (wave>>1)*32, wn = (wave&1)*32;
  f32x4 acc[2][2] = {};

  for (int kb=0; kb<K/64; kb++) {
    if (AMODE==0 && !bf16in) {
      const float* Af = (const float*)Araw;
      #pragma unroll
      for (int it=0; it<4; it++) {
        int c = it*256 + tid;
        int r = c>>4, cc = (c&15)*4;
        float4 v = *(const float4*)&Af[(size_t)(m0+r)*K + kb*64 + cc];
        u16 h0=f2bf(v.x), h1=f2bf(v.y), h2=f2bf(v.z), h3=f2bf(v.w);
        *(ushort4*)&Ah[r*72+cc] = make_ushort4(h0,h1,h2,h3);
        *(ushort4*)&Al[r*72+cc] = make_ushort4(
            f2bf(v.x-bf2f(h0)), f2bf(v.y-bf2f(h1)),
            f2bf(v.z-bf2f(h2)), f2bf(v.w-bf2f(h3)));
      }
    } else {
      const u16* Ab = (const u16*)Araw;
      #pragma unroll
      for (int it=0; it<2; it++) {
        int c = it*256 + tid;
        int r = c>>3, cc = (c&7)*8;
        *(bf16x8*)&Ah[r*72+cc] = *(const bf16x8*)&Ab[(size_t)(m0+r)*K + kb*64 + cc];
      }
    }
    if (!bf16in) {
      const float* Wf = (const float*)Wraw + (size_t)dir*G3*K;
      #pragma unroll
      for (int it=0; it<4; it++) {
        int c = it*256 + tid;
        int r = c>>4, cc = (c&15)*4;
        float4 v = *(const float4*)&Wf[(size_t)(n0+r)*K + kb*64 + cc];
        u16 h0=f2bf(v.x), h1=f2bf(v.y), h2=f2bf(v.z), h3=f2bf(v.w);
        *(ushort4*)&Wh[r*72+cc] = make_ushort4(h0,h1,h2,h3);
        *(ushort4*)&Wl[r*72+cc] = make_ushort4(
            f2bf(v.x-bf2f(h0)), f2bf(v.y-bf2f(h1)),
            f2bf(v.z-bf2f(h2)), f2bf(v.w-bf2f(h3)));
      }
    } else {
      const u16* Wb = (const u16*)Wraw + (size_t)dir*G3*K;
      #pragma unroll
      for (int it=0; it<2; it++) {
        int c = it*256 + tid;
        int r = c>>3, cc = (c&7)*8;
        *(bf16x8*)&Wh[r*72+cc] = *(const bf16x8*)&Wb[(size_t)(n0+r)*K + kb*64 + cc];
      }
    }
    __syncthreads();
    #pragma unroll
    for (int ks=0; ks<2; ks++) {
      int ko = ks*32 + (lane>>4)*8;
      bf16x8 a0 = *(const bf16x8*)&Ah[(wm    + (lane&15))*72 + ko];
      bf16x8 a1 = *(const bf16x8*)&Ah[(wm+16 + (lane&15))*72 + ko];
      bf16x8 b0 = *(const bf16x8*)&Wh[(wn    + (lane&15))*72 + ko];
      bf16x8 b1 = *(const bf16x8*)&Wh[(wn+16 + (lane&15))*72 + ko];
      acc[0][0] = __builtin_amdgcn_mfma_f32_16x16x32_bf16(a0,b0,acc[0][0],0,0,0);
      acc[0][1] = __builtin_amdgcn_mfma_f32_16x16x32_bf16(a0,b1,acc[0][1],0,0,0);
      acc[1][0] = __builtin_amdgcn_mfma_f32_16x16x32_bf16(a1,b0,acc[1][0],0,0,0);
      acc[1][1] = __builtin_amdgcn_mfma_f32_16x16x32_bf16(a1,b1,acc[1][1],0,0,0);
      if (useAlo) {
        bf16x8 c0 = *(const bf16x8*)&Al[(wm    + (lane&15))*72 + ko];
        bf16x8 c1 = *(const bf16x8*)&Al[(wm+16 + (lane&15))*72 + ko];
        acc[0][0] = __builtin_amdgcn_mfma_f32_16x16x32_bf16(c0,b0,acc[0][0],0,0,0);
        acc[0][1] = __builtin_amdgcn_mfma_f32_16x16x32_bf16(c0,b1,acc[0][1],0,0,0);
        acc[1][0] = __builtin_amdgcn_mfma_f32_16x16x32_bf16(c1,b0,acc[1][0],0,0,0);
        acc[1][1] = __builtin_amdgcn_mfma_f32_16x16x32_bf16(c1,b1,acc[1][1],0,0,0);
      }
      if (useWlo) {
        bf16x8 d0 = *(const bf16x8*)&Wl[(wn    + (lane&15))*72 + ko];
        bf16x8 d1 = *(const bf16x8*)&Wl[(wn+16 + (lane&15))*72 + ko];
        acc[0][0] = __builtin_amdgcn_mfma_f32_16x16x32_bf16(a0,d0,acc[0][0],0,0,0);
        acc[0][1] = __builtin_amdgcn_mfma_f32_16x16x32_bf16(a0,d1,acc[0][1],0,0,0);
        acc[1][0] = __builtin_amdgcn_mfma_f32_16x16x32_bf16(a1,d0,acc[1][0],0,0,0);
        acc[1][1] = __builtin_amdgcn_mfma_f32_16x16x32_bf16(a1,d1,acc[1][1],0,0,0);
      }
    }
    __syncthreads();
  }
  #pragma unroll
  for (int i=0;i<2;i++) {
    #pragma unroll
    for (int j=0;j<2;j++) {
      int nn = n0 + wn + j*16 + (lane&15);
      float bv = bf16in ? bf2f(((const u16*)braw)[dir*G3 + nn])
                        : ((const float*)braw)[dir*G3 + nn];
      #pragma unroll
      for (int r=0;r<4;r++) {
        int mm = m0 + wm + i*16 + (lane>>4)*4 + r;
        int b = mm >> 9, t = mm & 511;
        size_t oi = ((size_t)(dir*Tq + t)*Bq + b)*G3 + nn;
        float v = acc[i][j][r] + bv;
        if (OUTF32) ((float*)outraw)[oi] = v;
        else        ((u16*)outraw)[oi]   = f2bf(v);
      }
    }
  }
}

// ---------------------------------------------------------------------------
// Persistent GRU scan. 128 wgs: dir(2) x batch-group(4) x slice(16).
// ALL-RMW coherence-point protocol (round-4 PASS, fence now removed):
// every cross-block access (publish, signal, poll, gather) is an RMW that
// executes at the MALL -- the single serialization point. Chain:
//   exchange completes at MALL -> (vmcnt drain) -> signal add at MALL ->
//   poll RMW observes count -> gather RMWs read MALL state (later in MALL
//   order than the exchanges) -> fresh data. No buffer_inv / buffer_wbl2
//   anywhere in the loop. Round-5 lesson: 128 blocks/16 batches is the
//   right shape (256-block split doubled MALL RMW contention, +56% step).
// Poll uses s_sleep backoff so poll RMWs don't queue ahead of signal RMWs.
// Numerics bit-identical to rounds 2/4 (same single MFMA chain).
// ---------------------------------------------------------------------------
template<int LAYER, int GXF32>
__global__ __launch_bounds__(384,1) void gru_scan(const void* __restrict__ whh,
        const void* __restrict__ bhh, const void* __restrict__ gx,
        u16* __restrict__ hs0, void* __restrict__ dout,
        u32* __restrict__ hexw, int* __restrict__ flags,
        const int* __restrict__ dflag)
{
  extern __shared__ char smem[];
  u16*   wlds = (u16*)smem;                 // 96 x 520 bf16 = 99840 B
  u16*   ht   = (u16*)(smem + 99840);       // 16 x 520 bf16 = 16640 B
  float* ghl  = (float*)(smem + 116480);    // 16 x 100 f32  =  6400 B
  float* bhl  = (float*)(smem + 122880);    // 96 f32        =   384 B (total 123264)
  u32*   htw  = (u32*)ht;

  const int bf16in = dflag[0];
  const int tid = threadIdx.x;
  const int bx  = blockIdx.x;
  const int dir = bx>>6, group=(bx>>4)&3, slice=bx&15;
  const int jbase = slice*32, bg0 = group*16;
  int* fl = flags + (dir*4+group)*16;

  if (!bf16in) {
    const float* wf = (const float*)whh + (size_t)dir*G3*Hq;
    for (int c = tid; c < 96*128; c += 384) {
      int r = c>>7, q = (c&127)*4;
      int gate = r>>5, jj = r&31;
      float4 v = *(const float4*)&wf[(size_t)(gate*512 + jbase + jj)*Hq + q];
      *(ushort4*)&wlds[r*520 + q] = make_ushort4(f2bf(v.x),f2bf(v.y),f2bf(v.z),f2bf(v.w));
    }
  } else {
    const u16* wb = (const u16*)whh + (size_t)dir*G3*Hq;
    for (int c = tid; c < 96*64; c += 384) {
      int r = c>>6, cc = (c&63)*8;
      int gate = r>>5, jj = r&31;
      *(bf16x8*)&wlds[r*520 + cc] = *(const bf16x8*)&wb[(size_t)(gate*512 + jbase + jj)*Hq + cc];
    }
  }
  if (tid < 96) {
    int gate = tid>>5, jj = tid&31;
    int off = dir*G3 + gate*512 + jbase + jj;
    bhl[tid] = bf16in ? bf2f(((const u16*)bhh)[off]) : ((const float*)bhh)[off];
  }
  __syncthreads();

  const int lane = tid&63;
  const int n0w = (tid>>6)*16;   // 6 waves cover 96 gate columns

  // per-thread element ownership (static across all steps -> h lives in regs)
  const int e0 = tid,       b0 = e0>>5, j0 = e0&31;        // always valid
  const int e1 = tid + 384, b1 = e1>>5, j1 = e1&31;        // valid if tid<128
  const bool has1 = (tid < 128);
  float h0 = 0.f, h1v = 0.f;
  float gr0,gz0,gn0, gr1,gz1,gn1;
  gr0=gz0=gn0=gr1=gz1=gn1=0.f;

  auto ldgx = [&](int t_in_, int b, int j, float& gr, float& gz, float& gn){
    size_t gbase = ((size_t)(dir*Tq + t_in_)*Bq + (bg0 + b))*G3 + jbase + j;
    if (GXF32) { const float* gp=(const float*)gx + gbase; gr=gp[0]; gz=gp[512]; gn=gp[1024]; }
    else       { const u16* gp=(const u16*)gx + gbase; gr=bf2f(gp[0]); gz=bf2f(gp[512]); gn=bf2f(gp[1024]); }
  };
  {
    int t0 = dir ? (Tq-1) : 0;
    ldgx(t0, b0, j0, gr0, gz0, gn0);
    if (has1) ldgx(t0, b1, j1, gr1, gz1, gn1);
  }

  for (int s=0; s<Tq; s++) {
    const int t_in = dir ? (Tq-1-s) : s;
    // RMW poll with sleep backoff: fresh at MALL, low RMW queue pressure.
    if (tid < 16) {
      while (__hip_atomic_fetch_add(&fl[tid], 0, __ATOMIC_RELAXED, __HIP_MEMORY_SCOPE_AGENT) < 6*s) {
        __builtin_amdgcn_s_sleep(1);
      }
    }
    __syncthreads();                                   // (A) flags -> gather
    {
      const u32 rb = (u32)(((s&1)*2 + dir)*Bq + bg0)*256u;
      for (int c = tid; c < 16*128; c += 384) {
        int r = c>>7, w2 = c&127;
        // RMW gather: executes at MALL -> always fresh, no fence needed.
        u64 v = __hip_atomic_fetch_add((u64*)&hexw[rb + (u32)r*256u + (u32)(2*w2)],
                                  (u64)0, __ATOMIC_RELAXED, __HIP_MEMORY_SCOPE_AGENT);
        *(u64*)&htw[r*260 + 2*w2] = v;
      }
    }
    __syncthreads();                                   // (B) gather -> MFMA
    f32x4 acc = {0.f,0.f,0.f,0.f};
    #pragma unroll
    for (int kk=0; kk<16; kk++) {
      int ko = kk*32 + (lane>>4)*8;
      bf16x8 a = *(const bf16x8*)&ht  [ (lane&15)       *520 + ko];
      bf16x8 b = *(const bf16x8*)&wlds[(n0w + (lane&15))*520 + ko];
      acc = __builtin_amdgcn_mfma_f32_16x16x32_bf16(a,b,acc,0,0,0);
    }
    #pragma unroll
    for (int r=0;r<4;r++) ghl[((lane>>4)*4 + r)*100 + n0w + (lane&15)] = acc[r];
    __syncthreads();                                   // (C) ghl -> elementwise

    // ---- elementwise (gx already in registers), h carried in registers ----
    const u32 rb2 = (u32)((((s+1)&1)*2 + dir)*Bq + bg0)*256u;
    float hn0 = 0.f, hn1 = 0.f;
    u16 hb0 = 0, hb1 = 0;
    {
      float rr = gr0 + ghl[b0*100 + j0]      + bhl[j0];
      float zz = gz0 + ghl[b0*100 + 32 + j0] + bhl[32 + j0];
      float gh =       ghl[b0*100 + 64 + j0] + bhl[64 + j0];
      float r = 1.f/(1.f + __expf(-rr));
      float z = 1.f/(1.f + __expf(-zz));
      float x = gn0 + r*gh;
      x = fminf(fmaxf(x, -15.f), 15.f);
      float e2 = __expf(2.f*x);
      float n = (e2 - 1.f)/(e2 + 1.f);
      hn0 = (1.f - z)*n + z*h0;
      h0 = hn0; hb0 = f2bf(hn0);
    }
    if (has1) {
      float rr = gr1 + ghl[b1*100 + j1]      + bhl[j1];
      float zz = gz1 + ghl[b1*100 + 32 + j1] + bhl[32 + j1];
      float gh =       ghl[b1*100 + 64 + j1] + bhl[64 + j1];
      float r = 1.f/(1.f + __expf(-rr));
      float z = 1.f/(1.f + __expf(-zz));
      float x = gn1 + r*gh;
      x = fminf(fmaxf(x, -15.f), 15.f);
      float e2 = __expf(2.f*x);
      float n = (e2 - 1.f)/(e2 + 1.f);
      hn1 = (1.f - z)*n + z*h1v;
      h1v = hn1; hb1 = f2bf(hn1);
    }
    // ---- publish h pairs via atomic EXCHANGE (executes+acks at MALL) ----
    {
      int v0 = hb0;
      int up0 = __shfl_down(v0, 1);
      if ((tid & 1) == 0) {
        (void)__hip_atomic_exchange(&hexw[rb2 + (u32)b0*256u + (u32)(slice*16 + (j0>>1))],
                           (u32)(v0 & 0xffff) | ((u32)up0 << 16),
                           __ATOMIC_RELAXED, __HIP_MEMORY_SCOPE_AGENT);
      }
      if (has1) {
        int v1 = hb1;
        int up1 = __shfl_down(v1, 1);
        if ((tid & 1) == 0) {
          (void)__hip_atomic_exchange(&hexw[rb2 + (u32)b1*256u + (u32)(slice*16 + (j1>>1))],
                             (u32)(v1 & 0xffff) | ((u32)up1 << 16),
                             __ATOMIC_RELAXED, __HIP_MEMORY_SCOPE_AGENT);
        }
      }
    }
    // per-wave: drain this wave's exchanges (acked at MALL), then signal.
    asm volatile("s_waitcnt vmcnt(0)" ::: "memory");
    if ((tid & 63) == 0) {
      (void)__hip_atomic_fetch_add(&fl[slice], 1, __ATOMIC_RELAXED, __HIP_MEMORY_SCOPE_AGENT);
    }

    // ---- prefetch next step's gx (hides under next poll/exchange) ----
    if (s+1 < Tq) {
      int tn = dir ? (Tq-2-s) : (s+1);
      ldgx(tn, b0, j0, gr0, gz0, gn0);
      if (has1) ldgx(tn, b1, j1, gr1, gz1, gn1);
    }

    // ---- off-critical-path output stores (nontemporal: keep L2 clean) ----
    {
      int bg = bg0 + b0;
      size_t oi = ((size_t)bg*Tq + t_in)*1024 + dir*512 + jbase + j0;
      if (LAYER==0) {
        __builtin_nontemporal_store(hb0, &hs0[oi]);
      } else {
        if (bf16in) __builtin_nontemporal_store(hb0, &((u16*)dout)[oi]);
        else        __builtin_nontemporal_store(hn0, &((float*)dout)[oi]);
      }
      if (s == Tq-1) {
        size_t hyi = (size_t)Bq*Tq*1024 + ((size_t)(LAYER*2 + dir)*Bq + bg)*512 + jbase + j0;
        if (bf16in) ((u16*)dout)[hyi] = hb0;
        else        ((float*)dout)[hyi] = hn0;
      }
    }
    if (has1) {
      int bg = bg0 + b1;
      size_t oi = ((size_t)bg*Tq + t_in)*1024 + dir*512 + jbase + j1;
      if (LAYER==0) {
        __builtin_nontemporal_store(hb1, &hs0[oi]);
      } else {
        if (bf16in) __builtin_nontemporal_store(hb1, &((u16*)dout)[oi]);
        else        __builtin_nontemporal_store(hn1, &((float*)dout)[oi]);
      }
      if (s == Tq-1) {
        size_t hyi = (size_t)Bq*Tq*1024 + ((size_t)(LAYER*2 + dir)*Bq + bg)*512 + jbase + j1;
        if (bf16in) ((u16*)dout)[hyi] = hb1;
        else        ((float*)dout)[hyi] = hn1;
      }
    }
  }
}

__global__ void init_k(u32* hexw, int* flags){
  int i = blockIdx.x*256 + threadIdx.x;
  if (i < 2*2*Bq*256) hexw[i] = 0;
  if (i < 128) flags[i] = 0;
}

extern "C" void kernel_launch(void* const* d_in, const int* in_sizes, int n_in,
                              void* d_out, int out_size, void* d_ws, size_t ws_size,
                              hipStream_t stream)
{
  const void* xs    = d_in[0];
  const void* w_ih0 = d_in[1];
  const void* w_hh0 = d_in[2];
  const void* b_ih0 = d_in[3];
  const void* b_hh0 = d_in[4];
  const void* w_ih1 = d_in[5];
  const void* w_hh1 = d_in[6];
  const void* b_ih1 = d_in[7];
  const void* b_hh1 = d_in[8];
  (void)in_sizes; (void)n_in; (void)out_size;

  // ws layout, smalls first: dflag @0, flags @256, hexw @1024 (262144 B),
  // gx @263168: fp32 (402653184 B) if it fits, else bf16 (201326592 B).
  char* ws   = (char*)d_ws;
  int* dflag = (int*)ws;
  int* flags = (int*)(ws + 256);
  u32* hexw  = (u32*)(ws + 1024);
  void* gx   = (void*)(ws + 263168ULL);
  const bool gxf32 = ws_size >= 263168ULL + 402653184ULL;
  // hs0: bf16 scratch in d_out bytes [0, 67 MB); gemm1 consumes it before
  // scan1 overwrites d_out with h1_out (stream-ordered).
  u16* hs0   = (u16*)d_out;

  hipFuncSetAttribute((const void*)gru_scan<0,0>, hipFuncAttributeMaxDynamicSharedMemorySize, 123264);
  hipFuncSetAttribute((const void*)gru_scan<1,0>, hipFuncAttributeMaxDynamicSharedMemorySize, 123264);
  hipFuncSetAttribute((const void*)gru_scan<0,1>, hipFuncAttributeMaxDynamicSharedMemorySize, 123264);
  hipFuncSetAttribute((const void*)gru_scan<1,1>, hipFuncAttributeMaxDynamicSharedMemorySize, 123264);

  dim3 gg(Tq*Bq/64, G3/64, 2);   // (512, 24, 2)

  detect_k<<<1, 256, 0, stream>>>((const u16*)xs, dflag);
  init_k<<<512, 256, 0, stream>>>(hexw, flags);
  if (gxf32) {
    gemm_gx<512,0,1><<<gg, 256, 0, stream>>>(xs, w_ih0, b_ih0, gx, dflag);
    gru_scan<0,1><<<128, 384, 123264, stream>>>(w_hh0, b_hh0, gx, hs0, d_out, hexw, flags, dflag);
    gemm_gx<1024,1,1><<<gg, 256, 0, stream>>>(hs0, w_ih1, b_ih1, gx, dflag);
    init_k<<<512, 256, 0, stream>>>(hexw, flags);
    gru_scan<1,1><<<128, 384, 123264, stream>>>(w_hh1, b_hh1, gx, hs0, d_out, hexw, flags, dflag);
  } else {
    gemm_gx<512,0,0><<<gg, 256, 0, stream>>>(xs, w_ih0, b_ih0, gx, dflag);
    gru_scan<0,0><<<128, 384, 123264, stream>>>(w_hh0, b_hh0, gx, hs0, d_out, hexw, flags, dflag);
    gemm_gx<1024,1,0><<<gg, 256, 0, stream>>>(hs0, w_ih1, b_ih1, gx, dflag);
    init_k<<<512, 256, 0, stream>>>(hexw, flags);
    gru_scan<1,0><<<128, 384, 123264, stream>>>(w_hh1, b_hh1, gx, hs0, d_out, hexw, flags, dflag);
  }
}

// Round 7
// 6818.967 us; speedup vs baseline: 2.2229x; 1.0225x over previous
//
#include <hip/hip_runtime.h>
#include <stdint.h>

#define Bq 64
#define Tq 512
#define Hq 512
#define G3 1536

typedef unsigned short u16;
typedef uint32_t u32;
typedef unsigned long long u64;
typedef __attribute__((ext_vector_type(8))) short bf16x8;
typedef __attribute__((ext_vector_type(4))) float f32x4;

__device__ __forceinline__ float bf2f(u16 v){ unsigned u = ((unsigned)v)<<16; float f; __builtin_memcpy(&f,&u,4); return f; }
__device__ __forceinline__ u16 f2bf(float f){ unsigned u; __builtin_memcpy(&u,&f,4); u += 0x7fffu + ((u>>16)&1u); return (u16)(u>>16); }

// dtype detector: flag=1 if inputs are bf16, 0 if fp32.
__global__ void detect_k(const u16* __restrict__ xs, int* __restrict__ flag){
  __shared__ int cnt;
  if (threadIdx.x==0) cnt = 0;
  __syncthreads();
  int good = 0;
  for (int i = threadIdx.x; i < 4096; i += 256) {
    u16 v = xs[2*i];
    int e = (v>>7)&0xFF;
    if (e==0 || (e>=100 && e<=140)) good++;
  }
  atomicAdd(&cnt, good);
  __syncthreads();
  if (threadIdx.x==0) flag[0] = (cnt > 3600) ? 1 : 0;
}

// ---------------------------------------------------------------------------
// gx GEMM: gx[dir][t][b][n] = A[b*T+t][:] . W[dir][n][:] + bias[dir][n]
// AMODE 0: A dtype per flag (fp32 -> split hi/lo bf16). AMODE 1: A bf16 (hs0).
// OUTF32: gx stored fp32 (1) or bf16 (0).
// ---------------------------------------------------------------------------
template<int K, int AMODE, int OUTF32>
__global__ __launch_bounds__(256,1) void gemm_gx(const void* __restrict__ Araw,
        const void* __restrict__ Wraw, const void* __restrict__ braw,
        void* __restrict__ outraw, const int* __restrict__ dflag)
{
  __shared__ __align__(16) u16 Ah[64*72];
  __shared__ __align__(16) u16 Al[64*72];
  __shared__ __align__(16) u16 Wh[64*72];
  __shared__ __align__(16) u16 Wl[64*72];
  const int bf16in = dflag[0];
  const bool useAlo = (AMODE==0) && !bf16in;
  const bool useWlo = !bf16in;
  const int dir = blockIdx.z;
  const int tid = threadIdx.x;
  const int m0 = blockIdx.x*64, n0 = blockIdx.y*64;
  const int wave = tid>>6, lane = tid&63;
  const int wm = (wave>>1)*32, wn = (wave&1)*32;
  f32x4 acc[2][2] = {};

  for (int kb=0; kb<K/64; kb++) {
    if (AMODE==0 && !bf16in) {
      const float* Af = (const float*)Araw;
      #pragma unroll
      for (int it=0; it<4; it++) {
        int c = it*256 + tid;
        int r = c>>4, cc = (c&15)*4;
        float4 v = *(const float4*)&Af[(size_t)(m0+r)*K + kb*64 + cc];
        u16 h0=f2bf(v.x), h1=f2bf(v.y), h2=f2bf(v.z), h3=f2bf(v.w);
        *(ushort4*)&Ah[r*72+cc] = make_ushort4(h0,h1,h2,h3);
        *(ushort4*)&Al[r*72+cc] = make_ushort4(
            f2bf(v.x-bf2f(h0)), f2bf(v.y-bf2f(h1)),
            f2bf(v.z-bf2f(h2)), f2bf(v.w-bf2f(h3)));
      }
    } else {
      const u16* Ab = (const u16*)Araw;
      #pragma unroll
      for (int it=0; it<2; it++) {
        int c = it*256 + tid;
        int r = c>>3, cc = (c&7)*8;
        *(bf16x8*)&Ah[r*72+cc] = *(const bf16x8*)&Ab[(size_t)(m0+r)*K + kb*64 + cc];
      }
    }
    if (!bf16in) {
      const float* Wf = (const float*)Wraw + (size_t)dir*G3*K;
      #pragma unroll
      for (int it=0; it<4; it++) {
        int c = it*256 + tid;
        int r = c>>4, cc = (c&15)*4;
        float4 v = *(const float4*)&Wf[(size_t)(n0+r)*K + kb*64 + cc];
        u16 h0=f2bf(v.x), h1=f2bf(v.y), h2=f2bf(v.z), h3=f2bf(v.w);
        *(ushort4*)&Wh[r*72+cc] = make_ushort4(h0,h1,h2,h3);
        *(ushort4*)&Wl[r*72+cc] = make_ushort4(
            f2bf(v.x-bf2f(h0)), f2bf(v.y-bf2f(h1)),
            f2bf(v.z-bf2f(h2)), f2bf(v.w-bf2f(h3)));
      }
    } else {
      const u16* Wb = (const u16*)Wraw + (size_t)dir*G3*K;
      #pragma unroll
      for (int it=0; it<2; it++) {
        int c = it*256 + tid;
        int r = c>>3, cc = (c&7)*8;
        *(bf16x8*)&Wh[r*72+cc] = *(const bf16x8*)&Wb[(size_t)(n0+r)*K + kb*64 + cc];
      }
    }
    __syncthreads();
    #pragma unroll
    for (int ks=0; ks<2; ks++) {
      int ko = ks*32 + (lane>>4)*8;
      bf16x8 a0 = *(const bf16x8*)&Ah[(wm    + (lane&15))*72 + ko];
      bf16x8 a1 = *(const bf16x8*)&Ah[(wm+16 + (lane&15))*72 + ko];
      bf16x8 b0 = *(const bf16x8*)&Wh[(wn    + (lane&15))*72 + ko];
      bf16x8 b1 = *(const bf16x8*)&Wh[(wn+16 + (lane&15))*72 + ko];
      acc[0][0] = __builtin_amdgcn_mfma_f32_16x16x32_bf16(a0,b0,acc[0][0],0,0,0);
      acc[0][1] = __builtin_amdgcn_mfma_f32_16x16x32_bf16(a0,b1,acc[0][1],0,0,0);
      acc[1][0] = __builtin_amdgcn_mfma_f32_16x16x32_bf16(a1,b0,acc[1][0],0,0,0);
      acc[1][1] = __builtin_amdgcn_mfma_f32_16x16x32_bf16(a1,b1,acc[1][1],0,0,0);
      if (useAlo) {
        bf16x8 c0 = *(const bf16x8*)&Al[(wm    + (lane&15))*72 + ko];
        bf16x8 c1 = *(const bf16x8*)&Al[(wm+16 + (lane&15))*72 + ko];
        acc[0][0] = __builtin_amdgcn_mfma_f32_16x16x32_bf16(c0,b0,acc[0][0],0,0,0);
        acc[0][1] = __builtin_amdgcn_mfma_f32_16x16x32_bf16(c0,b1,acc[0][1],0,0,0);
        acc[1][0] = __builtin_amdgcn_mfma_f32_16x16x32_bf16(c1,b0,acc[1][0],0,0,0);
        acc[1][1] = __builtin_amdgcn_mfma_f32_16x16x32_bf16(c1,b1,acc[1][1],0,0,0);
      }
      if (useWlo) {
        bf16x8 d0 = *(const bf16x8*)&Wl[(wn    + (lane&15))*72 + ko];
        bf16x8 d1 = *(const bf16x8*)&Wl[(wn+16 + (lane&15))*72 + ko];
        acc[0][0] = __builtin_amdgcn_mfma_f32_16x16x32_bf16(a0,d0,acc[0][0],0,0,0);
        acc[0][1] = __builtin_amdgcn_mfma_f32_16x16x32_bf16(a0,d1,acc[0][1],0,0,0);
        acc[1][0] = __builtin_amdgcn_mfma_f32_16x16x32_bf16(a1,d0,acc[1][0],0,0,0);
        acc[1][1] = __builtin_amdgcn_mfma_f32_16x16x32_bf16(a1,d1,acc[1][1],0,0,0);
      }
    }
    __syncthreads();
  }
  #pragma unroll
  for (int i=0;i<2;i++) {
    #pragma unroll
    for (int j=0;j<2;j++) {
      int nn = n0 + wn + j*16 + (lane&15);
      float bv = bf16in ? bf2f(((const u16*)braw)[dir*G3 + nn])
                        : ((const float*)braw)[dir*G3 + nn];
      #pragma unroll
      for (int r=0;r<4;r++) {
        int mm = m0 + wm + i*16 + (lane>>4)*4 + r;
        int b = mm >> 9, t = mm & 511;
        size_t oi = ((size_t)(dir*Tq + t)*Bq + b)*G3 + nn;
        float v = acc[i][j][r] + bv;
        if (OUTF32) ((float*)outraw)[oi] = v;
        else        ((u16*)outraw)[oi]   = f2bf(v);
      }
    }
  }
}

// ---------------------------------------------------------------------------
// Persistent GRU scan. 128 wgs: dir(2) x batch-group(4) x slice(16).
// ALL-RMW coherence-point protocol (round-6 PASS, unchanged):
//   publish exchanges + signal adds + poll RMWs + gather RMWs all execute at
//   the MALL; ordering = per-wave vmcnt drain before signal; no fences.
// Round-7 changes (protocol untouched, numerics bit-identical):
//   - W_hh lives in REGISTERS (16x bf16x8 per lane, statically indexed,
//     loop-invariant) -> no wlds, MFMA phase reads only ht from LDS.
//   - publishes packed 4 h per u64 exchange (160 vs 320 ops/block-step).
// ---------------------------------------------------------------------------
template<int LAYER, int GXF32>
__global__ __launch_bounds__(384,1) void gru_scan(const void* __restrict__ whh,
        const void* __restrict__ bhh, const void* __restrict__ gx,
        u16* __restrict__ hs0, void* __restrict__ dout,
        u32* __restrict__ hexw, int* __restrict__ flags,
        const int* __restrict__ dflag)
{
  extern __shared__ char smem[];
  u16*   ht   = (u16*)smem;                 // 16 x 520 bf16 = 16640 B
  float* ghl  = (float*)(smem + 16640);     // 16 x 100 f32  =  6400 B
  float* bhl  = (float*)(smem + 23040);     // 96 f32        =   384 B (total 23424)
  u32*   htw  = (u32*)ht;

  const int bf16in = dflag[0];
  const int tid = threadIdx.x;
  const int bx  = blockIdx.x;
  const int dir = bx>>6, group=(bx>>4)&3, slice=bx&15;
  const int jbase = slice*32, bg0 = group*16;
  int* fl = flags + (dir*4+group)*16;

  const int lane = tid&63;
  const int n0w = (tid>>6)*16;   // 6 waves cover 96 gate columns

  // ---- W_hh fragments in registers (loop-invariant, statically indexed) ----
  // Lane owns gate-col n = n0w+(lane&15), K-chunk offset (lane>>4)*8 within
  // each 32-wide kk block: identical values to the old wlds layout.
  bf16x8 wreg[16];
  {
    const int n = n0w + (lane&15);
    const int gate = n>>5, jj = n&31;
    const int khalf = (lane>>4)*8;
    if (!bf16in) {
      const float* wf = (const float*)whh + (size_t)dir*G3*Hq
                      + (size_t)(gate*512 + jbase + jj)*Hq;
      #pragma unroll
      for (int kk=0; kk<16; kk++) {
        float4 v0 = *(const float4*)&wf[kk*32 + khalf];
        float4 v1 = *(const float4*)&wf[kk*32 + khalf + 4];
        bf16x8 w;
        w[0]=(short)f2bf(v0.x); w[1]=(short)f2bf(v0.y);
        w[2]=(short)f2bf(v0.z); w[3]=(short)f2bf(v0.w);
        w[4]=(short)f2bf(v1.x); w[5]=(short)f2bf(v1.y);
        w[6]=(short)f2bf(v1.z); w[7]=(short)f2bf(v1.w);
        wreg[kk] = w;
      }
    } else {
      const u16* wb = (const u16*)whh + (size_t)dir*G3*Hq
                    + (size_t)(gate*512 + jbase + jj)*Hq;
      #pragma unroll
      for (int kk=0; kk<16; kk++)
        wreg[kk] = *(const bf16x8*)&wb[kk*32 + khalf];
    }
  }
  if (tid < 96) {
    int gate = tid>>5, jj = tid&31;
    int off = dir*G3 + gate*512 + jbase + jj;
    bhl[tid] = bf16in ? bf2f(((const u16*)bhh)[off]) : ((const float*)bhh)[off];
  }
  __syncthreads();

  // per-thread element ownership (static across all steps -> h lives in regs)
  const int e0 = tid,       b0 = e0>>5, j0 = e0&31;        // always valid
  const int e1 = tid + 384, b1 = e1>>5, j1 = e1&31;        // valid if tid<128
  const bool has1 = (tid < 128);
  float h0 = 0.f, h1v = 0.f;
  float gr0,gz0,gn0, gr1,gz1,gn1;
  gr0=gz0=gn0=gr1=gz1=gn1=0.f;

  auto ldgx = [&](int t_in_, int b, int j, float& gr, float& gz, float& gn){
    size_t gbase = ((size_t)(dir*Tq + t_in_)*Bq + (bg0 + b))*G3 + jbase + j;
    if (GXF32) { const float* gp=(const float*)gx + gbase; gr=gp[0]; gz=gp[512]; gn=gp[1024]; }
    else       { const u16* gp=(const u16*)gx + gbase; gr=bf2f(gp[0]); gz=bf2f(gp[512]); gn=bf2f(gp[1024]); }
  };
  {
    int t0 = dir ? (Tq-1) : 0;
    ldgx(t0, b0, j0, gr0, gz0, gn0);
    if (has1) ldgx(t0, b1, j1, gr1, gz1, gn1);
  }

  for (int s=0; s<Tq; s++) {
    const int t_in = dir ? (Tq-1-s) : s;
    // RMW poll with sleep backoff: fresh at MALL, low RMW queue pressure.
    if (tid < 16) {
      while (__hip_atomic_fetch_add(&fl[tid], 0, __ATOMIC_RELAXED, __HIP_MEMORY_SCOPE_AGENT) < 6*s) {
        __builtin_amdgcn_s_sleep(1);
      }
    }
    __syncthreads();                                   // (A) flags -> gather
    {
      const u32 rb = (u32)(((s&1)*2 + dir)*Bq + bg0)*256u;
      for (int c = tid; c < 16*128; c += 384) {
        int r = c>>7, w2 = c&127;
        // RMW gather: executes at MALL -> always fresh, no fence needed.
        u64 v = __hip_atomic_fetch_add((u64*)&hexw[rb + (u32)r*256u + (u32)(2*w2)],
                                  (u64)0, __ATOMIC_RELAXED, __HIP_MEMORY_SCOPE_AGENT);
        *(u64*)&htw[r*260 + 2*w2] = v;
      }
    }
    __syncthreads();                                   // (B) gather -> MFMA
    f32x4 acc = {0.f,0.f,0.f,0.f};
    #pragma unroll
    for (int kk=0; kk<16; kk++) {
      int ko = kk*32 + (lane>>4)*8;
      bf16x8 a = *(const bf16x8*)&ht[(lane&15)*520 + ko];
      acc = __builtin_amdgcn_mfma_f32_16x16x32_bf16(a,wreg[kk],acc,0,0,0);
    }
    #pragma unroll
    for (int r=0;r<4;r++) ghl[((lane>>4)*4 + r)*100 + n0w + (lane&15)] = acc[r];
    __syncthreads();                                   // (C) ghl -> elementwise

    // ---- elementwise (gx already in registers), h carried in registers ----
    const u32 rb2 = (u32)((((s+1)&1)*2 + dir)*Bq + bg0)*256u;
    float hn0 = 0.f, hn1 = 0.f;
    u16 hb0 = 0, hb1 = 0;
    {
      float rr = gr0 + ghl[b0*100 + j0]      + bhl[j0];
      float zz = gz0 + ghl[b0*100 + 32 + j0] + bhl[32 + j0];
      float gh =       ghl[b0*100 + 64 + j0] + bhl[64 + j0];
      float r = 1.f/(1.f + __expf(-rr));
      float z = 1.f/(1.f + __expf(-zz));
      float x = gn0 + r*gh;
      x = fminf(fmaxf(x, -15.f), 15.f);
      float e2 = __expf(2.f*x);
      float n = (e2 - 1.f)/(e2 + 1.f);
      hn0 = (1.f - z)*n + z*h0;
      h0 = hn0; hb0 = f2bf(hn0);
    }
    if (has1) {
      float rr = gr1 + ghl[b1*100 + j1]      + bhl[j1];
      float zz = gz1 + ghl[b1*100 + 32 + j1] + bhl[32 + j1];
      float gh =       ghl[b1*100 + 64 + j1] + bhl[64 + j1];
      float r = 1.f/(1.f + __expf(-rr));
      float z = 1.f/(1.f + __expf(-zz));
      float x = gn1 + r*gh;
      x = fminf(fmaxf(x, -15.f), 15.f);
      float e2 = __expf(2.f*x);
      float n = (e2 - 1.f)/(e2 + 1.f);
      hn1 = (1.f - z)*n + z*h1v;
      h1v = hn1; hb1 = f2bf(hn1);
    }
    // ---- publish 4 h per u64 atomic EXCHANGE (executes+acks at MALL) ----
    {
      u32 p1 = (u32)__shfl_down((int)hb0, 1);
      u32 p2 = (u32)__shfl_down((int)hb0, 2);
      u32 p3 = (u32)__shfl_down((int)hb0, 3);
      if ((tid & 3) == 0) {
        u64 pk = (u64)hb0 | ((u64)(p1 & 0xffffu) << 16)
               | ((u64)(p2 & 0xffffu) << 32) | ((u64)(p3 & 0xffffu) << 48);
        (void)__hip_atomic_exchange((u64*)&hexw[rb2 + (u32)b0*256u + (u32)(slice*16 + (j0>>1))],
                                    pk, __ATOMIC_RELAXED, __HIP_MEMORY_SCOPE_AGENT);
      }
      if (has1) {
        u32 q1 = (u32)__shfl_down((int)hb1, 1);
        u32 q2 = (u32)__shfl_down((int)hb1, 2);
        u32 q3 = (u32)__shfl_down((int)hb1, 3);
        if ((tid & 3) == 0) {
          u64 pk = (u64)hb1 | ((u64)(q1 & 0xffffu) << 16)
                 | ((u64)(q2 & 0xffffu) << 32) | ((u64)(q3 & 0xffffu) << 48);
          (void)__hip_atomic_exchange((u64*)&hexw[rb2 + (u32)b1*256u + (u32)(slice*16 + (j1>>1))],
                                      pk, __ATOMIC_RELAXED, __HIP_MEMORY_SCOPE_AGENT);
        }
      }
    }
    // per-wave: drain this wave's exchanges (acked at MALL), then signal.
    asm volatile("s_waitcnt vmcnt(0)" ::: "memory");
    if ((tid & 63) == 0) {
      (void)__hip_atomic_fetch_add(&fl[slice], 1, __ATOMIC_RELAXED, __HIP_MEMORY_SCOPE_AGENT);
    }

    // ---- prefetch next step's gx (hides under next poll/exchange) ----
    if (s+1 < Tq) {
      int tn = dir ? (Tq-2-s) : (s+1);
      ldgx(tn, b0, j0, gr0, gz0, gn0);
      if (has1) ldgx(tn, b1, j1, gr1, gz1, gn1);
    }

    // ---- off-critical-path output stores (nontemporal: keep L2 clean) ----
    {
      int bg = bg0 + b0;
      size_t oi = ((size_t)bg*Tq + t_in)*1024 + dir*512 + jbase + j0;
      if (LAYER==0) {
        __builtin_nontemporal_store(hb0, &hs0[oi]);
      } else {
        if (bf16in) __builtin_nontemporal_store(hb0, &((u16*)dout)[oi]);
        else        __builtin_nontemporal_store(hn0, &((float*)dout)[oi]);
      }
      if (s == Tq-1) {
        size_t hyi = (size_t)Bq*Tq*1024 + ((size_t)(LAYER*2 + dir)*Bq + bg)*512 + jbase + j0;
        if (bf16in) ((u16*)dout)[hyi] = hb0;
        else        ((float*)dout)[hyi] = hn0;
      }
    }
    if (has1) {
      int bg = bg0 + b1;
      size_t oi = ((size_t)bg*Tq + t_in)*1024 + dir*512 + jbase + j1;
      if (LAYER==0) {
        __builtin_nontemporal_store(hb1, &hs0[oi]);
      } else {
        if (bf16in) __builtin_nontemporal_store(hb1, &((u16*)dout)[oi]);
        else        __builtin_nontemporal_store(hn1, &((float*)dout)[oi]);
      }
      if (s == Tq-1) {
        size_t hyi = (size_t)Bq*Tq*1024 + ((size_t)(LAYER*2 + dir)*Bq + bg)*512 + jbase + j1;
        if (bf16in) ((u16*)dout)[hyi] = hb1;
        else        ((float*)dout)[hyi] = hn1;
      }
    }
  }
}

__global__ void init_k(u32* hexw, int* flags){
  int i = blockIdx.x*256 + threadIdx.x;
  if (i < 2*2*Bq*256) hexw[i] = 0;
  if (i < 128) flags[i] = 0;
}

extern "C" void kernel_launch(void* const* d_in, const int* in_sizes, int n_in,
                              void* d_out, int out_size, void* d_ws, size_t ws_size,
                              hipStream_t stream)
{
  const void* xs    = d_in[0];
  const void* w_ih0 = d_in[1];
  const void* w_hh0 = d_in[2];
  const void* b_ih0 = d_in[3];
  const void* b_hh0 = d_in[4];
  const void* w_ih1 = d_in[5];
  const void* w_hh1 = d_in[6];
  const void* b_ih1 = d_in[7];
  const void* b_hh1 = d_in[8];
  (void)in_sizes; (void)n_in; (void)out_size;

  // ws layout, smalls first: dflag @0, flags @256, hexw @1024 (262144 B),
  // gx @263168: fp32 (402653184 B) if it fits, else bf16 (201326592 B).
  char* ws   = (char*)d_ws;
  int* dflag = (int*)ws;
  int* flags = (int*)(ws + 256);
  u32* hexw  = (u32*)(ws + 1024);
  void* gx   = (void*)(ws + 263168ULL);
  const bool gxf32 = ws_size >= 263168ULL + 402653184ULL;
  // hs0: bf16 scratch in d_out bytes [0, 67 MB); gemm1 consumes it before
  // scan1 overwrites d_out with h1_out (stream-ordered).
  u16* hs0   = (u16*)d_out;

  dim3 gg(Tq*Bq/64, G3/64, 2);   // (512, 24, 2)

  detect_k<<<1, 256, 0, stream>>>((const u16*)xs, dflag);
  init_k<<<512, 256, 0, stream>>>(hexw, flags);
  if (gxf32) {
    gemm_gx<512,0,1><<<gg, 256, 0, stream>>>(xs, w_ih0, b_ih0, gx, dflag);
    gru_scan<0,1><<<128, 384, 23424, stream>>>(w_hh0, b_hh0, gx, hs0, d_out, hexw, flags, dflag);
    gemm_gx<1024,1,1><<<gg, 256, 0, stream>>>(hs0, w_ih1, b_ih1, gx, dflag);
    init_k<<<512, 256, 0, stream>>>(hexw, flags);
    gru_scan<1,1><<<128, 384, 23424, stream>>>(w_hh1, b_hh1, gx, hs0, d_out, hexw, flags, dflag);
  } else {
    gemm_gx<512,0,0><<<gg, 256, 0, stream>>>(xs, w_ih0, b_ih0, gx, dflag);
    gru_scan<0,0><<<128, 384, 23424, stream>>>(w_hh0, b_hh0, gx, hs0, d_out, hexw, flags, dflag);
    gemm_gx<1024,1,0><<<gg, 256, 0, stream>>>(hs0, w_ih1, b_ih1, gx, dflag);
    init_k<<<512, 256, 0, stream>>>(hexw, flags);
    gru_scan<1,0><<<128, 384, 23424, stream>>>(w_hh1, b_hh1, gx, hs0, d_out, hexw, flags, dflag);
  }
}

// Round 8
// 6283.022 us; speedup vs baseline: 2.4125x; 1.0853x over previous
//
#include <hip/hip_runtime.h>
#include <stdint.h>

#define Bq 64
#define Tq 512
#define Hq 512
#define G3 1536

typedef unsigned short u16;
typedef uint32_t u32;
typedef unsigned long long u64;
typedef __attribute__((ext_vector_type(8))) short bf16x8;
typedef __attribute__((ext_vector_type(4))) float f32x4;

__device__ __forceinline__ float bf2f(u16 v){ unsigned u = ((unsigned)v)<<16; float f; __builtin_memcpy(&f,&u,4); return f; }
__device__ __forceinline__ u16 f2bf(float f){ unsigned u; __builtin_memcpy(&u,&f,4); u += 0x7fffu + ((u>>16)&1u); return (u16)(u>>16); }

// dtype detector: flag=1 if inputs are bf16, 0 if fp32.
__global__ void detect_k(const u16* __restrict__ xs, int* __restrict__ flag){
  __shared__ int cnt;
  if (threadIdx.x==0) cnt = 0;
  __syncthreads();
  int good = 0;
  for (int i = threadIdx.x; i < 4096; i += 256) {
    u16 v = xs[2*i];
    int e = (v>>7)&0xFF;
    if (e==0 || (e>=100 && e<=140)) good++;
  }
  atomicAdd(&cnt, good);
  __syncthreads();
  if (threadIdx.x==0) flag[0] = (cnt > 3600) ? 1 : 0;
}

// ---------------------------------------------------------------------------
// gx GEMM: gx[dir][t][b][n] = A[b*T+t][:] . W[dir][n][:] + bias[dir][n]
// AMODE 0: A dtype per flag (fp32 -> split hi/lo bf16). AMODE 1: A bf16 (hs0).
// OUTF32: gx stored fp32 (1) or bf16 (0).
// ---------------------------------------------------------------------------
template<int K, int AMODE, int OUTF32>
__global__ __launch_bounds__(256,1) void gemm_gx(const void* __restrict__ Araw,
        const void* __restrict__ Wraw, const void* __restrict__ braw,
        void* __restrict__ outraw, const int* __restrict__ dflag)
{
  __shared__ __align__(16) u16 Ah[64*72];
  __shared__ __align__(16) u16 Al[64*72];
  __shared__ __align__(16) u16 Wh[64*72];
  __shared__ __align__(16) u16 Wl[64*72];
  const int bf16in = dflag[0];
  const bool useAlo = (AMODE==0) && !bf16in;
  const bool useWlo = !bf16in;
  const int dir = blockIdx.z;
  const int tid = threadIdx.x;
  const int m0 = blockIdx.x*64, n0 = blockIdx.y*64;
  const int wave = tid>>6, lane = tid&63;
  const int wm = (wave>>1)*32, wn = (wave&1)*32;
  f32x4 acc[2][2] = {};

  for (int kb=0; kb<K/64; kb++) {
    if (AMODE==0 && !bf16in) {
      const float* Af = (const float*)Araw;
      #pragma unroll
      for (int it=0; it<4; it++) {
        int c = it*256 + tid;
        int r = c>>4, cc = (c&15)*4;
        float4 v = *(const float4*)&Af[(size_t)(m0+r)*K + kb*64 + cc];
        u16 h0=f2bf(v.x), h1=f2bf(v.y), h2=f2bf(v.z), h3=f2bf(v.w);
        *(ushort4*)&Ah[r*72+cc] = make_ushort4(h0,h1,h2,h3);
        *(ushort4*)&Al[r*72+cc] = make_ushort4(
            f2bf(v.x-bf2f(h0)), f2bf(v.y-bf2f(h1)),
            f2bf(v.z-bf2f(h2)), f2bf(v.w-bf2f(h3)));
      }
    } else {
      const u16* Ab = (const u16*)Araw;
      #pragma unroll
      for (int it=0; it<2; it++) {
        int c = it*256 + tid;
        int r = c>>3, cc = (c&7)*8;
        *(bf16x8*)&Ah[r*72+cc] = *(const bf16x8*)&Ab[(size_t)(m0+r)*K + kb*64 + cc];
      }
    }
    if (!bf16in) {
      const float* Wf = (const float*)Wraw + (size_t)dir*G3*K;
      #pragma unroll
      for (int it=0; it<4; it++) {
        int c = it*256 + tid;
        int r = c>>4, cc = (c&15)*4;
        float4 v = *(const float4*)&Wf[(size_t)(n0+r)*K + kb*64 + cc];
        u16 h0=f2bf(v.x), h1=f2bf(v.y), h2=f2bf(v.z), h3=f2bf(v.w);
        *(ushort4*)&Wh[r*72+cc] = make_ushort4(h0,h1,h2,h3);
        *(ushort4*)&Wl[r*72+cc] = make_ushort4(
            f2bf(v.x-bf2f(h0)), f2bf(v.y-bf2f(h1)),
            f2bf(v.z-bf2f(h2)), f2bf(v.w-bf2f(h3)));
      }
    } else {
      const u16* Wb = (const u16*)Wraw + (size_t)dir*G3*K;
      #pragma unroll
      for (int it=0; it<2; it++) {
        int c = it*256 + tid;
        int r = c>>3, cc = (c&7)*8;
        *(bf16x8*)&Wh[r*72+cc] = *(const bf16x8*)&Wb[(size_t)(n0+r)*K + kb*64 + cc];
      }
    }
    __syncthreads();
    #pragma unroll
    for (int ks=0; ks<2; ks++) {
      int ko = ks*32 + (lane>>4)*8;
      bf16x8 a0 = *(const bf16x8*)&Ah[(wm    + (lane&15))*72 + ko];
      bf16x8 a1 = *(const bf16x8*)&Ah[(wm+16 + (lane&15))*72 + ko];
      bf16x8 b0 = *(const bf16x8*)&Wh[(wn    + (lane&15))*72 + ko];
      bf16x8 b1 = *(const bf16x8*)&Wh[(wn+16 + (lane&15))*72 + ko];
      acc[0][0] = __builtin_amdgcn_mfma_f32_16x16x32_bf16(a0,b0,acc[0][0],0,0,0);
      acc[0][1] = __builtin_amdgcn_mfma_f32_16x16x32_bf16(a0,b1,acc[0][1],0,0,0);
      acc[1][0] = __builtin_amdgcn_mfma_f32_16x16x32_bf16(a1,b0,acc[1][0],0,0,0);
      acc[1][1] = __builtin_amdgcn_mfma_f32_16x16x32_bf16(a1,b1,acc[1][1],0,0,0);
      if (useAlo) {
        bf16x8 c0 = *(const bf16x8*)&Al[(wm    + (lane&15))*72 + ko];
        bf16x8 c1 = *(const bf16x8*)&Al[(wm+16 + (lane&15))*72 + ko];
        acc[0][0] = __builtin_amdgcn_mfma_f32_16x16x32_bf16(c0,b0,acc[0][0],0,0,0);
        acc[0][1] = __builtin_amdgcn_mfma_f32_16x16x32_bf16(c0,b1,acc[0][1],0,0,0);
        acc[1][0] = __builtin_amdgcn_mfma_f32_16x16x32_bf16(c1,b0,acc[1][0],0,0,0);
        acc[1][1] = __builtin_amdgcn_mfma_f32_16x16x32_bf16(c1,b1,acc[1][1],0,0,0);
      }
      if (useWlo) {
        bf16x8 d0 = *(const bf16x8*)&Wl[(wn    + (lane&15))*72 + ko];
        bf16x8 d1 = *(const bf16x8*)&Wl[(wn+16 + (lane&15))*72 + ko];
        acc[0][0] = __builtin_amdgcn_mfma_f32_16x16x32_bf16(a0,d0,acc[0][0],0,0,0);
        acc[0][1] = __builtin_amdgcn_mfma_f32_16x16x32_bf16(a0,d1,acc[0][1],0,0,0);
        acc[1][0] = __builtin_amdgcn_mfma_f32_16x16x32_bf16(a1,d0,acc[1][0],0,0,0);
        acc[1][1] = __builtin_amdgcn_mfma_f32_16x16x32_bf16(a1,d1,acc[1][1],0,0,0);
      }
    }
    __syncthreads();
  }
  #pragma unroll
  for (int i=0;i<2;i++) {
    #pragma unroll
    for (int j=0;j<2;j++) {
      int nn = n0 + wn + j*16 + (lane&15);
      float bv = bf16in ? bf2f(((const u16*)braw)[dir*G3 + nn])
                        : ((const float*)braw)[dir*G3 + nn];
      #pragma unroll
      for (int r=0;r<4;r++) {
        int mm = m0 + wm + i*16 + (lane>>4)*4 + r;
        int b = mm >> 9, t = mm & 511;
        size_t oi = ((size_t)(dir*Tq + t)*Bq + b)*G3 + nn;
        float v = acc[i][j][r] + bv;
        if (OUTF32) ((float*)outraw)[oi] = v;
        else        ((u16*)outraw)[oi]   = f2bf(v);
      }
    }
  }
}

// ---------------------------------------------------------------------------
// Persistent GRU scan. 128 wgs: dir(2) x batch-group(4) x slice(16).
// ALL-RMW coherence-point protocol (round-6/7 PASS, structure unchanged):
//   poll (RMW+sleep) -> barrier A -> RMW u64 gather -> barrier B ->
//   compute -> exchange publish -> per-wave vmcnt drain -> signal add.
// Round-8 restructure (numerics bit-identical):
//   FUSED-GATE MFMA: wave w in {0,1} computes tiles {w, w+2, w+4} = gates
//   r/z/n for cols j0 = 16w+(lane&15). Each lane then holds gh_r/z/n for
//   4 batches x its j0 IN REGISTERS -> elementwise fused right after the
//   MFMAs: no ghl staging, no barrier C, bias in 3 regs, publish from regs.
//   Only waves 0-1 publish -> 2 signals/block-step (poll target 2*s);
//   waves 2-5 are gather-helpers and idle through the compute phase.
//   Same per-tile 16-chain MFMA sequence in kk order -> gh bit-identical.
// ---------------------------------------------------------------------------
template<int LAYER, int GXF32>
__global__ __launch_bounds__(384,1) void gru_scan(const void* __restrict__ whh,
        const void* __restrict__ bhh, const void* __restrict__ gx,
        u16* __restrict__ hs0, void* __restrict__ dout,
        u32* __restrict__ hexw, int* __restrict__ flags,
        const int* __restrict__ dflag)
{
  extern __shared__ char smem[];
  u16*   wlds = (u16*)smem;                 // 96 x 520 bf16 = 99840 B
  u16*   ht   = (u16*)(smem + 99840);       // 16 x 520 bf16 = 16640 B (total 116480)
  u32*   htw  = (u32*)ht;

  const int bf16in = dflag[0];
  const int tid = threadIdx.x;
  const int bx  = blockIdx.x;
  const int dir = bx>>6, group=(bx>>4)&3, slice=bx&15;
  const int jbase = slice*32, bg0 = group*16;
  int* fl = flags + (dir*4+group)*16;

  if (!bf16in) {
    const float* wf = (const float*)whh + (size_t)dir*G3*Hq;
    for (int c = tid; c < 96*128; c += 384) {
      int r = c>>7, q = (c&127)*4;
      int gate = r>>5, jj = r&31;
      float4 v = *(const float4*)&wf[(size_t)(gate*512 + jbase + jj)*Hq + q];
      *(ushort4*)&wlds[r*520 + q] = make_ushort4(f2bf(v.x),f2bf(v.y),f2bf(v.z),f2bf(v.w));
    }
  } else {
    const u16* wb = (const u16*)whh + (size_t)dir*G3*Hq;
    for (int c = tid; c < 96*64; c += 384) {
      int r = c>>6, cc = (c&63)*8;
      int gate = r>>5, jj = r&31;
      *(bf16x8*)&wlds[r*520 + cc] = *(const bf16x8*)&wb[(size_t)(gate*512 + jbase + jj)*Hq + cc];
    }
  }
  __syncthreads();

  const int wave = tid>>6, lane = tid&63;
  const bool cw = (wave < 2);                 // compute waves
  const int j0 = wave*16 + (lane&15);         // col within slice [0,32) (cw only)
  const int bq = (lane>>4)*4;                 // batch base (0,4,8,12)

  // loop-invariant bias regs (compute waves)
  float bR=0.f, bZ=0.f, bN=0.f;
  if (cw) {
    int off = dir*G3 + jbase + j0;
    if (bf16in) { const u16* bb=(const u16*)bhh;
      bR=bf2f(bb[off]); bZ=bf2f(bb[off+512]); bN=bf2f(bb[off+1024]); }
    else { const float* bb=(const float*)bhh;
      bR=bb[off]; bZ=bb[off+512]; bN=bb[off+1024]; }
  }

  float h[4] = {0.f,0.f,0.f,0.f};
  float gxr[4], gxz[4], gxn[4];
  auto ldgx = [&](int t_in_){
    #pragma unroll
    for (int i=0;i<4;i++){
      size_t gb = ((size_t)(dir*Tq + t_in_)*Bq + (bg0 + bq + i))*G3 + jbase + j0;
      if (GXF32) { const float* gp=(const float*)gx + gb;
        gxr[i]=gp[0]; gxz[i]=gp[512]; gxn[i]=gp[1024]; }
      else { const u16* gp=(const u16*)gx + gb;
        gxr[i]=bf2f(gp[0]); gxz[i]=bf2f(gp[512]); gxn[i]=bf2f(gp[1024]); }
    }
  };
  if (cw) ldgx(dir ? (Tq-1) : 0);

  for (int s=0; s<Tq; s++) {
    const int t_in = dir ? (Tq-1-s) : s;
    // RMW poll with sleep backoff: fresh at MALL. 2 signals/block-step.
    if (tid < 16) {
      while (__hip_atomic_fetch_add(&fl[tid], 0, __ATOMIC_RELAXED, __HIP_MEMORY_SCOPE_AGENT) < 2*s) {
        __builtin_amdgcn_s_sleep(1);
      }
    }
    __syncthreads();                                   // (A) flags -> gather
    {
      const u32 rb = (u32)(((s&1)*2 + dir)*Bq + bg0)*256u;
      for (int c = tid; c < 16*128; c += 384) {
        int r = c>>7, w2 = c&127;
        u64 v = __hip_atomic_fetch_add((u64*)&hexw[rb + (u32)r*256u + (u32)(2*w2)],
                                  (u64)0, __ATOMIC_RELAXED, __HIP_MEMORY_SCOPE_AGENT);
        *(u64*)&htw[r*260 + 2*w2] = v;
      }
    }
    __syncthreads();                                   // (B) gather -> MFMA

    if (cw) {
      f32x4 aR = {0.f,0.f,0.f,0.f}, aZ = {0.f,0.f,0.f,0.f}, aN = {0.f,0.f,0.f,0.f};
      const int wl = wave*16 + (lane&15);
      #pragma unroll
      for (int kk=0; kk<16; kk++) {
        int ko = kk*32 + (lane>>4)*8;
        bf16x8 a  = *(const bf16x8*)&ht[(lane&15)*520 + ko];
        bf16x8 b0 = *(const bf16x8*)&wlds[(     wl)*520 + ko];
        bf16x8 b1 = *(const bf16x8*)&wlds[(32 + wl)*520 + ko];
        bf16x8 b2 = *(const bf16x8*)&wlds[(64 + wl)*520 + ko];
        aR = __builtin_amdgcn_mfma_f32_16x16x32_bf16(a,b0,aR,0,0,0);
        aZ = __builtin_amdgcn_mfma_f32_16x16x32_bf16(a,b1,aZ,0,0,0);
        aN = __builtin_amdgcn_mfma_f32_16x16x32_bf16(a,b2,aN,0,0,0);
      }
      // ---- fused elementwise: 4 batches, all in registers ----
      const u32 rb2 = (u32)((((s+1)&1)*2 + dir)*Bq + bg0)*256u;
      u16 hb[4]; float hn[4];
      #pragma unroll
      for (int i=0;i<4;i++) {
        float rr = gxr[i] + aR[i] + bR;
        float zz = gxz[i] + aZ[i] + bZ;
        float gh =          aN[i] + bN;
        float r = 1.f/(1.f + __expf(-rr));
        float z = 1.f/(1.f + __expf(-zz));
        float x = gxn[i] + r*gh;
        x = fminf(fmaxf(x, -15.f), 15.f);
        float e2 = __expf(2.f*x);
        float n = (e2 - 1.f)/(e2 + 1.f);
        hn[i] = (1.f - z)*n + z*h[i];
        h[i] = hn[i]; hb[i] = f2bf(hn[i]);
      }
      // ---- publish 4 j per u64 exchange (lane&3==0), straight from regs ----
      #pragma unroll
      for (int i=0;i<4;i++) {
        u32 p1 = (u32)__shfl_down((int)hb[i], 1);
        u32 p2 = (u32)__shfl_down((int)hb[i], 2);
        u32 p3 = (u32)__shfl_down((int)hb[i], 3);
        if ((lane & 3) == 0) {
          u64 pk = (u64)hb[i] | ((u64)(p1 & 0xffffu) << 16)
                 | ((u64)(p2 & 0xffffu) << 32) | ((u64)(p3 & 0xffffu) << 48);
          (void)__hip_atomic_exchange((u64*)&hexw[rb2 + (u32)(bq+i)*256u + (u32)(slice*16 + (j0>>1))],
                                      pk, __ATOMIC_RELAXED, __HIP_MEMORY_SCOPE_AGENT);
        }
      }
      // drain this wave's exchanges (acked at MALL), then signal.
      asm volatile("s_waitcnt vmcnt(0)" ::: "memory");
      if (lane == 0) {
        (void)__hip_atomic_fetch_add(&fl[slice], 1, __ATOMIC_RELAXED, __HIP_MEMORY_SCOPE_AGENT);
      }
      // ---- prefetch next step's gx (hides under next poll/gather) ----
      if (s+1 < Tq) ldgx(dir ? (Tq-2-s) : (s+1));
      // ---- off-critical-path output stores ----
      #pragma unroll
      for (int i=0;i<4;i++) {
        int bg = bg0 + bq + i;
        size_t oi = ((size_t)bg*Tq + t_in)*1024 + dir*512 + jbase + j0;
        if (LAYER==0) {
          __builtin_nontemporal_store(hb[i], &hs0[oi]);
        } else {
          if (bf16in) __builtin_nontemporal_store(hb[i], &((u16*)dout)[oi]);
          else        __builtin_nontemporal_store(hn[i], &((float*)dout)[oi]);
        }
        if (s == Tq-1) {
          size_t hyi = (size_t)Bq*Tq*1024 + ((size_t)(LAYER*2 + dir)*Bq + bg)*512 + jbase + j0;
          if (bf16in) ((u16*)dout)[hyi] = hb[i];
          else        ((float*)dout)[hyi] = hn[i];
        }
      }
    }
  }
}

__global__ void init_k(u32* hexw, int* flags){
  int i = blockIdx.x*256 + threadIdx.x;
  if (i < 2*2*Bq*256) hexw[i] = 0;
  if (i < 128) flags[i] = 0;
}

extern "C" void kernel_launch(void* const* d_in, const int* in_sizes, int n_in,
                              void* d_out, int out_size, void* d_ws, size_t ws_size,
                              hipStream_t stream)
{
  const void* xs    = d_in[0];
  const void* w_ih0 = d_in[1];
  const void* w_hh0 = d_in[2];
  const void* b_ih0 = d_in[3];
  const void* b_hh0 = d_in[4];
  const void* w_ih1 = d_in[5];
  const void* w_hh1 = d_in[6];
  const void* b_ih1 = d_in[7];
  const void* b_hh1 = d_in[8];
  (void)in_sizes; (void)n_in; (void)out_size;

  // ws layout, smalls first: dflag @0, flags @256, hexw @1024 (262144 B),
  // gx @263168: fp32 (402653184 B) if it fits, else bf16 (201326592 B).
  char* ws   = (char*)d_ws;
  int* dflag = (int*)ws;
  int* flags = (int*)(ws + 256);
  u32* hexw  = (u32*)(ws + 1024);
  void* gx   = (void*)(ws + 263168ULL);
  const bool gxf32 = ws_size >= 263168ULL + 402653184ULL;
  // hs0: bf16 scratch in d_out bytes [0, 67 MB); gemm1 consumes it before
  // scan1 overwrites d_out with h1_out (stream-ordered).
  u16* hs0   = (u16*)d_out;

  hipFuncSetAttribute((const void*)gru_scan<0,0>, hipFuncAttributeMaxDynamicSharedMemorySize, 116480);
  hipFuncSetAttribute((const void*)gru_scan<1,0>, hipFuncAttributeMaxDynamicSharedMemorySize, 116480);
  hipFuncSetAttribute((const void*)gru_scan<0,1>, hipFuncAttributeMaxDynamicSharedMemorySize, 116480);
  hipFuncSetAttribute((const void*)gru_scan<1,1>, hipFuncAttributeMaxDynamicSharedMemorySize, 116480);

  dim3 gg(Tq*Bq/64, G3/64, 2);   // (512, 24, 2)

  detect_k<<<1, 256, 0, stream>>>((const u16*)xs, dflag);
  init_k<<<512, 256, 0, stream>>>(hexw, flags);
  if (gxf32) {
    gemm_gx<512,0,1><<<gg, 256, 0, stream>>>(xs, w_ih0, b_ih0, gx, dflag);
    gru_scan<0,1><<<128, 384, 116480, stream>>>(w_hh0, b_hh0, gx, hs0, d_out, hexw, flags, dflag);
    gemm_gx<1024,1,1><<<gg, 256, 0, stream>>>(hs0, w_ih1, b_ih1, gx, dflag);
    init_k<<<512, 256, 0, stream>>>(hexw, flags);
    gru_scan<1,1><<<128, 384, 116480, stream>>>(w_hh1, b_hh1, gx, hs0, d_out, hexw, flags, dflag);
  } else {
    gemm_gx<512,0,0><<<gg, 256, 0, stream>>>(xs, w_ih0, b_ih0, gx, dflag);
    gru_scan<0,0><<<128, 384, 116480, stream>>>(w_hh0, b_hh0, gx, hs0, d_out, hexw, flags, dflag);
    gemm_gx<1024,1,0><<<gg, 256, 0, stream>>>(hs0, w_ih1, b_ih1, gx, dflag);
    init_k<<<512, 256, 0, stream>>>(hexw, flags);
    gru_scan<1,0><<<128, 384, 116480, stream>>>(w_hh1, b_hh1, gx, hs0, d_out, hexw, flags, dflag);
  }
}

// Round 9
// 6199.752 us; speedup vs baseline: 2.4449x; 1.0134x over previous
//
#include <hip/hip_runtime.h>
#include <stdint.h>

#define Bq 64
#define Tq 512
#define Hq 512
#define G3 1536

typedef unsigned short u16;
typedef uint32_t u32;
typedef unsigned long long u64;
typedef __attribute__((ext_vector_type(8))) short bf16x8;
typedef __attribute__((ext_vector_type(4))) float f32x4;

__device__ __forceinline__ float bf2f(u16 v){ unsigned u = ((unsigned)v)<<16; float f; __builtin_memcpy(&f,&u,4); return f; }
__device__ __forceinline__ u16 f2bf(float f){ unsigned u; __builtin_memcpy(&u,&f,4); u += 0x7fffu + ((u>>16)&1u); return (u16)(u>>16); }

// dtype detector: flag=1 if inputs are bf16, 0 if fp32.
__global__ void detect_k(const u16* __restrict__ xs, int* __restrict__ flag){
  __shared__ int cnt;
  if (threadIdx.x==0) cnt = 0;
  __syncthreads();
  int good = 0;
  for (int i = threadIdx.x; i < 4096; i += 256) {
    u16 v = xs[2*i];
    int e = (v>>7)&0xFF;
    if (e==0 || (e>=100 && e<=140)) good++;
  }
  atomicAdd(&cnt, good);
  __syncthreads();
  if (threadIdx.x==0) flag[0] = (cnt > 3600) ? 1 : 0;
}

// ---------------------------------------------------------------------------
// gx GEMM: gx[dir][t][b][n] = A[b*T+t][:] . W[dir][n][:] + bias[dir][n]
// AMODE 0: A dtype per flag (fp32 -> split hi/lo bf16). AMODE 1: A bf16 (hs0).
// OUTF32: gx stored fp32 (1) or bf16 (0).
// ---------------------------------------------------------------------------
template<int K, int AMODE, int OUTF32>
__global__ __launch_bounds__(256,1) void gemm_gx(const void* __restrict__ Araw,
        const void* __restrict__ Wraw, const void* __restrict__ braw,
        void* __restrict__ outraw, const int* __restrict__ dflag)
{
  __shared__ __align__(16) u16 Ah[64*72];
  __shared__ __align__(16) u16 Al[64*72];
  __shared__ __align__(16) u16 Wh[64*72];
  __shared__ __align__(16) u16 Wl[64*72];
  const int bf16in = dflag[0];
  const bool useAlo = (AMODE==0) && !bf16in;
  const bool useWlo = !bf16in;
  const int dir = blockIdx.z;
  const int tid = threadIdx.x;
  const int m0 = blockIdx.x*64, n0 = blockIdx.y*64;
  const int wave = tid>>6, lane = tid&63;
  const int wm = (wave>>1)*32, wn = (wave&1)*32;
  f32x4 acc[2][2] = {};

  for (int kb=0; kb<K/64; kb++) {
    if (AMODE==0 && !bf16in) {
      const float* Af = (const float*)Araw;
      #pragma unroll
      for (int it=0; it<4; it++) {
        int c = it*256 + tid;
        int r = c>>4, cc = (c&15)*4;
        float4 v = *(const float4*)&Af[(size_t)(m0+r)*K + kb*64 + cc];
        u16 h0=f2bf(v.x), h1=f2bf(v.y), h2=f2bf(v.z), h3=f2bf(v.w);
        *(ushort4*)&Ah[r*72+cc] = make_ushort4(h0,h1,h2,h3);
        *(ushort4*)&Al[r*72+cc] = make_ushort4(
            f2bf(v.x-bf2f(h0)), f2bf(v.y-bf2f(h1)),
            f2bf(v.z-bf2f(h2)), f2bf(v.w-bf2f(h3)));
      }
    } else {
      const u16* Ab = (const u16*)Araw;
      #pragma unroll
      for (int it=0; it<2; it++) {
        int c = it*256 + tid;
        int r = c>>3, cc = (c&7)*8;
        *(bf16x8*)&Ah[r*72+cc] = *(const bf16x8*)&Ab[(size_t)(m0+r)*K + kb*64 + cc];
      }
    }
    if (!bf16in) {
      const float* Wf = (const float*)Wraw + (size_t)dir*G3*K;
      #pragma unroll
      for (int it=0; it<4; it++) {
        int c = it*256 + tid;
        int r = c>>4, cc = (c&15)*4;
        float4 v = *(const float4*)&Wf[(size_t)(n0+r)*K + kb*64 + cc];
        u16 h0=f2bf(v.x), h1=f2bf(v.y), h2=f2bf(v.z), h3=f2bf(v.w);
        *(ushort4*)&Wh[r*72+cc] = make_ushort4(h0,h1,h2,h3);
        *(ushort4*)&Wl[r*72+cc] = make_ushort4(
            f2bf(v.x-bf2f(h0)), f2bf(v.y-bf2f(h1)),
            f2bf(v.z-bf2f(h2)), f2bf(v.w-bf2f(h3)));
      }
    } else {
      const u16* Wb = (const u16*)Wraw + (size_t)dir*G3*K;
      #pragma unroll
      for (int it=0; it<2; it++) {
        int c = it*256 + tid;
        int r = c>>3, cc = (c&7)*8;
        *(bf16x8*)&Wh[r*72+cc] = *(const bf16x8*)&Wb[(size_t)(n0+r)*K + kb*64 + cc];
      }
    }
    __syncthreads();
    #pragma unroll
    for (int ks=0; ks<2; ks++) {
      int ko = ks*32 + (lane>>4)*8;
      bf16x8 a0 = *(const bf16x8*)&Ah[(wm    + (lane&15))*72 + ko];
      bf16x8 a1 = *(const bf16x8*)&Ah[(wm+16 + (lane&15))*72 + ko];
      bf16x8 b0 = *(const bf16x8*)&Wh[(wn    + (lane&15))*72 + ko];
      bf16x8 b1 = *(const bf16x8*)&Wh[(wn+16 + (lane&15))*72 + ko];
      acc[0][0] = __builtin_amdgcn_mfma_f32_16x16x32_bf16(a0,b0,acc[0][0],0,0,0);
      acc[0][1] = __builtin_amdgcn_mfma_f32_16x16x32_bf16(a0,b1,acc[0][1],0,0,0);
      acc[1][0] = __builtin_amdgcn_mfma_f32_16x16x32_bf16(a1,b0,acc[1][0],0,0,0);
      acc[1][1] = __builtin_amdgcn_mfma_f32_16x16x32_bf16(a1,b1,acc[1][1],0,0,0);
      if (useAlo) {
        bf16x8 c0 = *(const bf16x8*)&Al[(wm    + (lane&15))*72 + ko];
        bf16x8 c1 = *(const bf16x8*)&Al[(wm+16 + (lane&15))*72 + ko];
        acc[0][0] = __builtin_amdgcn_mfma_f32_16x16x32_bf16(c0,b0,acc[0][0],0,0,0);
        acc[0][1] = __builtin_amdgcn_mfma_f32_16x16x32_bf16(c0,b1,acc[0][1],0,0,0);
        acc[1][0] = __builtin_amdgcn_mfma_f32_16x16x32_bf16(c1,b0,acc[1][0],0,0,0);
        acc[1][1] = __builtin_amdgcn_mfma_f32_16x16x32_bf16(c1,b1,acc[1][1],0,0,0);
      }
      if (useWlo) {
        bf16x8 d0 = *(const bf16x8*)&Wl[(wn    + (lane&15))*72 + ko];
        bf16x8 d1 = *(const bf16x8*)&Wl[(wn+16 + (lane&15))*72 + ko];
        acc[0][0] = __builtin_amdgcn_mfma_f32_16x16x32_bf16(a0,d0,acc[0][0],0,0,0);
        acc[0][1] = __builtin_amdgcn_mfma_f32_16x16x32_bf16(a0,d1,acc[0][1],0,0,0);
        acc[1][0] = __builtin_amdgcn_mfma_f32_16x16x32_bf16(a1,d0,acc[1][0],0,0,0);
        acc[1][1] = __builtin_amdgcn_mfma_f32_16x16x32_bf16(a1,d1,acc[1][1],0,0,0);
      }
    }
    __syncthreads();
  }
  #pragma unroll
  for (int i=0;i<2;i++) {
    #pragma unroll
    for (int j=0;j<2;j++) {
      int nn = n0 + wn + j*16 + (lane&15);
      float bv = bf16in ? bf2f(((const u16*)braw)[dir*G3 + nn])
                        : ((const float*)braw)[dir*G3 + nn];
      #pragma unroll
      for (int r=0;r<4;r++) {
        int mm = m0 + wm + i*16 + (lane>>4)*4 + r;
        int b = mm >> 9, t = mm & 511;
        size_t oi = ((size_t)(dir*Tq + t)*Bq + b)*G3 + nn;
        float v = acc[i][j][r] + bv;
        if (OUTF32) ((float*)outraw)[oi] = v;
        else        ((u16*)outraw)[oi]   = f2bf(v);
      }
    }
  }
}

// ---------------------------------------------------------------------------
// Persistent GRU scan. 128 wgs: dir(2) x batch-group(4) x slice(16).
// SINGLE-WAVE blocks (plus one helper wave that only stages weights then
// exits). ALL-RMW coherence-point protocol (rounds 6-8 PASS, unchanged):
// publish exchanges / signal adds / poll RMWs / gather RMWs all execute at
// the MALL; producer ordering = per-wave vmcnt drain before signal.
// Round-9 restructure (numerics bit-identical):
//  - The whole 16x512 h-tile fits ONE wave's A-fragments: lane holds
//    row=lane&15, cols kk*32+(lane>>4)*8 for kk=0..15 = 32 u64 RMW gathers
//    straight into VGPRs -> NO ht LDS, NO __syncthreads in the loop
//    (divergent poll reconvergence is the intra-wave barrier).
//  - 6 MFMA chains (3 gates x 2 col-halves) per wave, kk ascending ->
//    bit-identical gh. Elementwise fused (8 elems/lane), publish from regs,
//    1 signal/block-step (poll target s).
// ---------------------------------------------------------------------------
template<int LAYER, int GXF32>
__global__ __launch_bounds__(128,1) void gru_scan(const void* __restrict__ whh,
        const void* __restrict__ bhh, const void* __restrict__ gx,
        u16* __restrict__ hs0, void* __restrict__ dout,
        u32* __restrict__ hexw, int* __restrict__ flags,
        const int* __restrict__ dflag)
{
  extern __shared__ char smem[];
  u16* wlds = (u16*)smem;                 // 96 x 520 bf16 = 99840 B

  const int bf16in = dflag[0];
  const int tid = threadIdx.x;
  const int bx  = blockIdx.x;
  const int dir = bx>>6, group=(bx>>4)&3, slice=bx&15;
  const int jbase = slice*32, bg0 = group*16;
  int* fl = flags + (dir*4+group)*16;

  // ---- weight staging (both waves), then helper wave exits ----
  if (!bf16in) {
    const float* wf = (const float*)whh + (size_t)dir*G3*Hq;
    for (int c = tid; c < 96*128; c += 128) {
      int r = c>>7, q = (c&127)*4;
      int gate = r>>5, jj = r&31;
      float4 v = *(const float4*)&wf[(size_t)(gate*512 + jbase + jj)*Hq + q];
      *(ushort4*)&wlds[r*520 + q] = make_ushort4(f2bf(v.x),f2bf(v.y),f2bf(v.z),f2bf(v.w));
    }
  } else {
    const u16* wb = (const u16*)whh + (size_t)dir*G3*Hq;
    for (int c = tid; c < 96*64; c += 128) {
      int r = c>>6, cc = (c&63)*8;
      int gate = r>>5, jj = r&31;
      *(bf16x8*)&wlds[r*520 + cc] = *(const bf16x8*)&wb[(size_t)(gate*512 + jbase + jj)*Hq + cc];
    }
  }
  __syncthreads();
  if (tid >= 64) return;                  // helper wave done

  const int lane = tid;                   // 0..63
  const int j0 = lane&15;
  const int bq = (lane>>4)*4;             // batch base 0,4,8,12

  // loop-invariant bias regs (both col-halves)
  float bR[2], bZ[2], bN[2];
  #pragma unroll
  for (int c=0;c<2;c++) {
    int off = dir*G3 + jbase + c*16 + j0;
    if (bf16in) { const u16* bb=(const u16*)bhh;
      bR[c]=bf2f(bb[off]); bZ[c]=bf2f(bb[off+512]); bN[c]=bf2f(bb[off+1024]); }
    else { const float* bb=(const float*)bhh;
      bR[c]=bb[off]; bZ[c]=bb[off+512]; bN[c]=bb[off+1024]; }
  }

  float h[2][4] = {};
  float gxr[2][4], gxz[2][4], gxn[2][4];
  auto ldgx = [&](int t_in_){
    #pragma unroll
    for (int c=0;c<2;c++)
    #pragma unroll
    for (int i=0;i<4;i++){
      size_t gb = ((size_t)(dir*Tq + t_in_)*Bq + (bg0 + bq + i))*G3 + jbase + c*16 + j0;
      if (GXF32) { const float* gp=(const float*)gx + gb;
        gxr[c][i]=gp[0]; gxz[c][i]=gp[512]; gxn[c][i]=gp[1024]; }
      else { const u16* gp=(const u16*)gx + gb;
        gxr[c][i]=bf2f(gp[0]); gxz[c][i]=bf2f(gp[512]); gxn[c][i]=bf2f(gp[1024]); }
    }
  };
  ldgx(dir ? (Tq-1) : 0);

  for (int s=0; s<Tq; s++) {
    const int t_in = dir ? (Tq-1-s) : s;
    // poll (lanes 0-15, RMW at MALL); reconvergence = intra-wave barrier.
    if (lane < 16) {
      while (__hip_atomic_fetch_add(&fl[lane], 0, __ATOMIC_RELAXED, __HIP_MEMORY_SCOPE_AGENT) < s) {
        __builtin_amdgcn_s_sleep(1);
      }
    }
    asm volatile("" ::: "memory");   // compiler-only: no hoisting of gathers
    // ---- issue all 32 A-fragment u64 RMW gathers straight into VGPRs ----
    const u32 rb = (u32)(((s&1)*2 + dir)*Bq + bg0)*256u;
    u64 areg[32];
    #pragma unroll
    for (int kk=0; kk<16; kk++) {
      u32 base = rb + (u32)(lane&15)*256u + (u32)(kk*16 + (lane>>4)*4);
      areg[2*kk]   = __hip_atomic_fetch_add((u64*)&hexw[base],   (u64)0, __ATOMIC_RELAXED, __HIP_MEMORY_SCOPE_AGENT);
      areg[2*kk+1] = __hip_atomic_fetch_add((u64*)&hexw[base+2], (u64)0, __ATOMIC_RELAXED, __HIP_MEMORY_SCOPE_AGENT);
    }
    // ---- 6 MFMA chains, fragments consumed in kk order as they return ----
    f32x4 aR[2] = {{0.f,0.f,0.f,0.f},{0.f,0.f,0.f,0.f}};
    f32x4 aZ[2] = {{0.f,0.f,0.f,0.f},{0.f,0.f,0.f,0.f}};
    f32x4 aN[2] = {{0.f,0.f,0.f,0.f},{0.f,0.f,0.f,0.f}};
    #pragma unroll
    for (int kk=0; kk<16; kk++) {
      union { u64 q[2]; bf16x8 v; } ab;
      ab.q[0] = areg[2*kk]; ab.q[1] = areg[2*kk+1];
      int ko = kk*32 + (lane>>4)*8;
      #pragma unroll
      for (int c=0;c<2;c++) {
        int wl = c*16 + j0;
        bf16x8 b0 = *(const bf16x8*)&wlds[(     wl)*520 + ko];
        bf16x8 b1 = *(const bf16x8*)&wlds[(32 + wl)*520 + ko];
        bf16x8 b2 = *(const bf16x8*)&wlds[(64 + wl)*520 + ko];
        aR[c] = __builtin_amdgcn_mfma_f32_16x16x32_bf16(ab.v,b0,aR[c],0,0,0);
        aZ[c] = __builtin_amdgcn_mfma_f32_16x16x32_bf16(ab.v,b1,aZ[c],0,0,0);
        aN[c] = __builtin_amdgcn_mfma_f32_16x16x32_bf16(ab.v,b2,aN[c],0,0,0);
      }
    }
    // ---- fused elementwise: 2 col-halves x 4 batches, all in registers ----
    const u32 rb2 = (u32)((((s+1)&1)*2 + dir)*Bq + bg0)*256u;
    u16 hb[2][4]; float hn[2][4];
    #pragma unroll
    for (int c=0;c<2;c++)
    #pragma unroll
    for (int i=0;i<4;i++) {
      float rr = gxr[c][i] + aR[c][i] + bR[c];
      float zz = gxz[c][i] + aZ[c][i] + bZ[c];
      float gh =             aN[c][i] + bN[c];
      float r = 1.f/(1.f + __expf(-rr));
      float z = 1.f/(1.f + __expf(-zz));
      float x = gxn[c][i] + r*gh;
      x = fminf(fmaxf(x, -15.f), 15.f);
      float e2 = __expf(2.f*x);
      float n = (e2 - 1.f)/(e2 + 1.f);
      hn[c][i] = (1.f - z)*n + z*h[c][i];
      h[c][i] = hn[c][i]; hb[c][i] = f2bf(hn[c][i]);
    }
    // ---- publish 4 cols per u64 exchange (lane&3==0), straight from regs ----
    #pragma unroll
    for (int c=0;c<2;c++)
    #pragma unroll
    for (int i=0;i<4;i++) {
      u32 p1 = (u32)__shfl_down((int)hb[c][i], 1);
      u32 p2 = (u32)__shfl_down((int)hb[c][i], 2);
      u32 p3 = (u32)__shfl_down((int)hb[c][i], 3);
      if ((lane & 3) == 0) {
        u64 pk = (u64)hb[c][i] | ((u64)(p1 & 0xffffu) << 16)
               | ((u64)(p2 & 0xffffu) << 32) | ((u64)(p3 & 0xffffu) << 48);
        (void)__hip_atomic_exchange((u64*)&hexw[rb2 + (u32)(bq+i)*256u + (u32)(slice*16 + c*8 + (j0>>1))],
                                    pk, __ATOMIC_RELAXED, __HIP_MEMORY_SCOPE_AGENT);
      }
    }
    // drain exchanges (acked at MALL), then single signal.
    asm volatile("s_waitcnt vmcnt(0)" ::: "memory");
    if (lane == 0) {
      (void)__hip_atomic_fetch_add(&fl[slice], 1, __ATOMIC_RELAXED, __HIP_MEMORY_SCOPE_AGENT);
    }
    // ---- prefetch next step's gx (hides under next poll/gather) ----
    if (s+1 < Tq) ldgx(dir ? (Tq-2-s) : (s+1));
    // ---- off-critical-path output stores ----
    #pragma unroll
    for (int c=0;c<2;c++)
    #pragma unroll
    for (int i=0;i<4;i++) {
      int bg = bg0 + bq + i;
      size_t oi = ((size_t)bg*Tq + t_in)*1024 + dir*512 + jbase + c*16 + j0;
      if (LAYER==0) {
        __builtin_nontemporal_store(hb[c][i], &hs0[oi]);
      } else {
        if (bf16in) __builtin_nontemporal_store(hb[c][i], &((u16*)dout)[oi]);
        else        __builtin_nontemporal_store(hn[c][i], &((float*)dout)[oi]);
      }
      if (s == Tq-1) {
        size_t hyi = (size_t)Bq*Tq*1024 + ((size_t)(LAYER*2 + dir)*Bq + bg)*512 + jbase + c*16 + j0;
        if (bf16in) ((u16*)dout)[hyi] = hb[c][i];
        else        ((float*)dout)[hyi] = hn[c][i];
      }
    }
  }
}

__global__ void init_k(u32* hexw, int* flags){
  int i = blockIdx.x*256 + threadIdx.x;
  if (i < 2*2*Bq*256) hexw[i] = 0;
  if (i < 128) flags[i] = 0;
}

extern "C" void kernel_launch(void* const* d_in, const int* in_sizes, int n_in,
                              void* d_out, int out_size, void* d_ws, size_t ws_size,
                              hipStream_t stream)
{
  const void* xs    = d_in[0];
  const void* w_ih0 = d_in[1];
  const void* w_hh0 = d_in[2];
  const void* b_ih0 = d_in[3];
  const void* b_hh0 = d_in[4];
  const void* w_ih1 = d_in[5];
  const void* w_hh1 = d_in[6];
  const void* b_ih1 = d_in[7];
  const void* b_hh1 = d_in[8];
  (void)in_sizes; (void)n_in; (void)out_size;

  // ws layout, smalls first: dflag @0, flags @256, hexw @1024 (262144 B),
  // gx @263168: fp32 (402653184 B) if it fits, else bf16 (201326592 B).
  char* ws   = (char*)d_ws;
  int* dflag = (int*)ws;
  int* flags = (int*)(ws + 256);
  u32* hexw  = (u32*)(ws + 1024);
  void* gx   = (void*)(ws + 263168ULL);
  const bool gxf32 = ws_size >= 263168ULL + 402653184ULL;
  // hs0: bf16 scratch in d_out bytes [0, 67 MB); gemm1 consumes it before
  // scan1 overwrites d_out with h1_out (stream-ordered).
  u16* hs0   = (u16*)d_out;

  hipFuncSetAttribute((const void*)gru_scan<0,0>, hipFuncAttributeMaxDynamicSharedMemorySize, 99840);
  hipFuncSetAttribute((const void*)gru_scan<1,0>, hipFuncAttributeMaxDynamicSharedMemorySize, 99840);
  hipFuncSetAttribute((const void*)gru_scan<0,1>, hipFuncAttributeMaxDynamicSharedMemorySize, 99840);
  hipFuncSetAttribute((const void*)gru_scan<1,1>, hipFuncAttributeMaxDynamicSharedMemorySize, 99840);

  dim3 gg(Tq*Bq/64, G3/64, 2);   // (512, 24, 2)

  detect_k<<<1, 256, 0, stream>>>((const u16*)xs, dflag);
  init_k<<<512, 256, 0, stream>>>(hexw, flags);
  if (gxf32) {
    gemm_gx<512,0,1><<<gg, 256, 0, stream>>>(xs, w_ih0, b_ih0, gx, dflag);
    gru_scan<0,1><<<128, 128, 99840, stream>>>(w_hh0, b_hh0, gx, hs0, d_out, hexw, flags, dflag);
    gemm_gx<1024,1,1><<<gg, 256, 0, stream>>>(hs0, w_ih1, b_ih1, gx, dflag);
    init_k<<<512, 256, 0, stream>>>(hexw, flags);
    gru_scan<1,1><<<128, 128, 99840, stream>>>(w_hh1, b_hh1, gx, hs0, d_out, hexw, flags, dflag);
  } else {
    gemm_gx<512,0,0><<<gg, 256, 0, stream>>>(xs, w_ih0, b_ih0, gx, dflag);
    gru_scan<0,0><<<128, 128, 99840, stream>>>(w_hh0, b_hh0, gx, hs0, d_out, hexw, flags, dflag);
    gemm_gx<1024,1,0><<<gg, 256, 0, stream>>>(hs0, w_ih1, b_ih1, gx, dflag);
    init_k<<<512, 256, 0, stream>>>(hexw, flags);
    gru_scan<1,0><<<128, 128, 99840, stream>>>(w_hh1, b_hh1, gx, hs0, d_out, hexw, flags, dflag);
  }
}